// Round 3
// baseline (568.353 us; speedup 1.0000x reference)
//
#include <hip/hip_runtime.h>
#include <hip/hip_bf16.h>

#define NN 50000
#define NE 800000
#define NC 128
#define NEG 0.2f
#define BN_EPS 1e-5f

typedef unsigned int u32;

// workspace layout (in floats)
#define OFF_H      0               // NN*NC
#define OFF_EX     6400000         // NE+NN
#define OFF_ACCUM  7250000         // NN*NC
#define OFF_ASRC   13650000        // NN
#define OFF_ADST   13700000        // NN
#define OFF_M      13750000        // NN (u32)
#define OFF_DENOM  13800000        // NN
#define OFF_GSUM   13850000        // 128
#define OFF_GSUMSQ 13850128        // 128
#define OFF_SRC    13850256        // NE (int)
#define OFF_DST    14650256        // NE (int)
#define OFF_END    15450256        // 61.8 MB

__device__ __forceinline__ u32 ford(float f) {
  u32 u = __float_as_uint(f);
  return (u & 0x80000000u) ? ~u : (u | 0x80000000u);
}
__device__ __forceinline__ float ford_inv(u32 u) {
  return __uint_as_float((u & 0x80000000u) ? (u ^ 0x80000000u) : ~u);
}

// ---- K-1: edge_index ingest, robust to int32 vs int64 ---------------------
__global__ __launch_bounds__(256) void k_convert(
    const void* __restrict__ ei_raw, int* __restrict__ srcd, int* __restrict__ dstd) {
  int i = blockIdx.x * 256 + threadIdx.x;
  if (i >= 2 * NE) return;
  // If data is int64, every u64 word is a node id < NN. If int32, word k is
  // lo | (next << 32) >= 2^32 unless next==0 (p ~= 2e-5); all-8 FP ~ 0.
  const unsigned long long* p64 = (const unsigned long long*)ei_raw;
  bool is64 = true;
#pragma unroll
  for (int k = 0; k < 8; ++k) is64 = is64 && (p64[k] < (unsigned long long)NN);
  int v;
  if (is64) v = (int)((const long long*)ei_raw)[i];
  else      v = ((const int*)ei_raw)[i];
  if (i < NE) srcd[i] = v;
  else        dstd[i - NE] = v;
}

// ---- K0: h = x @ W, fused a_src = h.att_src, a_dst = h.att_dst -------------
__global__ __launch_bounds__(256) void k_gemm(
    const float* __restrict__ x, const float* __restrict__ W,
    const float* __restrict__ attS, const float* __restrict__ attD,
    float* __restrict__ h, float* __restrict__ a_src, float* __restrict__ a_dst) {
  __shared__ float Wl[32 * NC];   // 16 KB: W rows k0..k0+31
  __shared__ float xl[16 * 32];   // 2 KB:  x tile 16 rows x 32 k
  const int t = threadIdx.x;
  const int c = t & 127;
  const int rh = t >> 7;          // 0/1: which 8-row half
  const int row0 = blockIdx.x * 16;

  float acc[8];
#pragma unroll
  for (int r = 0; r < 8; ++r) acc[r] = 0.f;

  for (int k0 = 0; k0 < NC; k0 += 32) {
    __syncthreads();
    for (int i = t; i < 32 * NC; i += 256) Wl[i] = W[k0 * NC + i];
    for (int i = t; i < 16 * 32; i += 256)
      xl[i] = x[(row0 + (i >> 5)) * NC + k0 + (i & 31)];
    __syncthreads();
#pragma unroll 8
    for (int kk = 0; kk < 32; ++kk) {
      float w = Wl[kk * NC + c];
#pragma unroll
      for (int r = 0; r < 8; ++r) acc[r] += xl[(rh * 8 + r) * 32 + kk] * w;
    }
  }

  const float aS = attS[c], aD = attD[c];
#pragma unroll
  for (int r = 0; r < 8; ++r) {
    int row = row0 + rh * 8 + r;
    h[row * NC + c] = acc[r];
    float s1 = acc[r] * aS, s2 = acc[r] * aD;
    for (int off = 32; off > 0; off >>= 1) {
      s1 += __shfl_down(s1, off);
      s2 += __shfl_down(s2, off);
    }
    if ((t & 63) == 0) {
      atomicAdd(&a_src[row], s1);
      atomicAdd(&a_dst[row], s2);
    }
  }
}

// ---- K1: segment max over dst --------------------------------------------
__global__ __launch_bounds__(256) void k_edge_max(
    const int* __restrict__ srcd, const int* __restrict__ dstd,
    const float* __restrict__ a_src, const float* __restrict__ a_dst,
    u32* __restrict__ m) {
  int gid = blockIdx.x * 256 + threadIdx.x;
  if (gid >= NE + NN) return;
  int s, d;
  if (gid < NE) { s = srcd[gid]; d = dstd[gid]; }
  else          { s = d = gid - NE; }
  float e = a_src[s] + a_dst[d];
  e = (e >= 0.f) ? e : NEG * e;
  atomicMax(&m[d], ford(e));
}

// ---- K2: ex = exp(e - m[dst]); denom[dst] += ex ---------------------------
__global__ __launch_bounds__(256) void k_expsum(
    const int* __restrict__ srcd, const int* __restrict__ dstd,
    const float* __restrict__ a_src, const float* __restrict__ a_dst,
    const u32* __restrict__ m, float* __restrict__ denom, float* __restrict__ ex) {
  int gid = blockIdx.x * 256 + threadIdx.x;
  if (gid >= NE + NN) return;
  int s, d;
  if (gid < NE) { s = srcd[gid]; d = dstd[gid]; }
  else          { s = d = gid - NE; }
  float e = a_src[s] + a_dst[d];
  e = (e >= 0.f) ? e : NEG * e;
  float v = __expf(e - ford_inv(m[d]));
  ex[gid] = v;
  atomicAdd(&denom[d], v);
}

// ---- K3: accum[dst] += alpha * h[src] (2 edges per block) -----------------
__global__ __launch_bounds__(256) void k_scatter(
    const int* __restrict__ srcd, const int* __restrict__ dstd,
    const float* __restrict__ ex, const float* __restrict__ denom,
    const float* __restrict__ h, float* __restrict__ accum) {
  int item = blockIdx.x * 2 + (threadIdx.x >> 7);
  if (item >= NE + NN) return;
  int c = threadIdx.x & 127;
  int s, d;
  if (item < NE) { s = srcd[item]; d = dstd[item]; }
  else           { s = d = item - NE; }
  float alpha = ex[item] / denom[d];
  atomicAdd(&accum[d * NC + c], alpha * h[s * NC + c]);
}

// ---- K4: per-channel sum / sumsq over nodes -------------------------------
__global__ __launch_bounds__(256) void k_stats(
    const float* __restrict__ accum, float* __restrict__ gsum,
    float* __restrict__ gsumsq) {
  __shared__ float sh[256], sh2[256];
  int c = threadIdx.x & 127, rh = threadIdx.x >> 7;
  float s = 0.f, ss = 0.f;
  for (int row = blockIdx.x * 2 + rh; row < NN; row += gridDim.x * 2) {
    float v = accum[row * NC + c];
    s += v;
    ss += v * v;
  }
  sh[threadIdx.x] = s;
  sh2[threadIdx.x] = ss;
  __syncthreads();
  if (threadIdx.x < 128) {
    s = sh[threadIdx.x] + sh[threadIdx.x + 128];
    ss = sh2[threadIdx.x] + sh2[threadIdx.x + 128];
    atomicAdd(&gsum[c], s);
    atomicAdd(&gsumsq[c], ss);
  }
}

// ---- K5: BatchNorm (training stats) + ReLU -> fp32 ------------------------
__global__ __launch_bounds__(256) void k_bn(
    const float* __restrict__ accum, const float* __restrict__ gsum,
    const float* __restrict__ gsumsq, const float* __restrict__ gamma,
    const float* __restrict__ beta, float* __restrict__ out) {
  int idx = blockIdx.x * 256 + threadIdx.x;
  if (idx >= NN * NC) return;
  int c = idx & 127;
  float mean = gsum[c] * (1.0f / NN);
  float var = gsumsq[c] * (1.0f / NN) - mean * mean;
  float inv = rsqrtf(var + BN_EPS);
  float y = (accum[idx] - mean) * inv * gamma[c] + beta[c];
  out[idx] = (y > 0.f) ? y : 0.f;
}

extern "C" void kernel_launch(void* const* d_in, const int* in_sizes, int n_in,
                              void* d_out, int out_size, void* d_ws, size_t ws_size,
                              hipStream_t stream) {
  const float* x    = (const float*)d_in[0];
  const void*  ei   = d_in[1];
  // d_in[2] = edge_attr (ignored: edge_dim=None in reference)
  const float* W    = (const float*)d_in[3];
  const float* attS = (const float*)d_in[4];
  const float* attD = (const float*)d_in[5];
  // d_in[6] = bias: cancels under BN mean-subtraction (and is zeros)
  const float* gamma = (const float*)d_in[7];
  const float* beta  = (const float*)d_in[8];

  float* ws     = (float*)d_ws;
  float* h      = ws + OFF_H;
  float* ex     = ws + OFF_EX;
  float* accum  = ws + OFF_ACCUM;
  float* a_src  = ws + OFF_ASRC;
  float* a_dst  = ws + OFF_ADST;
  u32*   m      = (u32*)(ws + OFF_M);
  float* denom  = ws + OFF_DENOM;
  float* gsum   = ws + OFF_GSUM;
  float* gsumsq = ws + OFF_GSUMSQ;
  int*   srcd   = (int*)(ws + OFF_SRC);
  int*   dstd   = (int*)(ws + OFF_DST);

  // zero everything that is accumulated into (accum .. gsumsq end)
  hipMemsetAsync(accum, 0, (size_t)(OFF_SRC - OFF_ACCUM) * sizeof(float), stream);

  k_convert<<<(2 * NE + 255) / 256, 256, 0, stream>>>(ei, srcd, dstd);
  k_gemm<<<NN / 16, 256, 0, stream>>>(x, W, attS, attD, h, a_src, a_dst);
  int ne_blocks = (NE + NN + 255) / 256;
  k_edge_max<<<ne_blocks, 256, 0, stream>>>(srcd, dstd, a_src, a_dst, m);
  k_expsum<<<ne_blocks, 256, 0, stream>>>(srcd, dstd, a_src, a_dst, m, denom, ex);
  k_scatter<<<(NE + NN + 1) / 2, 256, 0, stream>>>(srcd, dstd, ex, denom, h, accum);
  k_stats<<<512, 256, 0, stream>>>(accum, gsum, gsumsq);
  k_bn<<<(NN * NC + 255) / 256, 256, 0, stream>>>(accum, gsum, gsumsq, gamma, beta,
                                                  (float*)d_out);
}

// Round 4
// 424.595 us; speedup vs baseline: 1.3386x; 1.3386x over previous
//
#include <hip/hip_runtime.h>
#include <hip/hip_bf16.h>

#define NN 50000
#define NE 800000
#define NC 128
#define NEG 0.2f
#define BN_EPS 1e-5f

typedef unsigned int u32;

// workspace layout (4-byte units)
#define OFF_H      0               // NN*NC floats
#define OFF_ACCUM  6400000         // NN*NC floats
#define OFF_ASRC   12800000        // NN
#define OFF_ADST   12850000        // NN
#define OFF_DEG    12900000        // NN (int)
#define OFF_GSUM   12950000        // 128
#define OFF_GSUMSQ 12950128        // 128
// ---- end of zeroed region (ASRC..GSUMSQ) ----
#define OFF_ROWPTR 12950256        // NN+1 (int)
#define OFF_CURSOR 13000257        // NN (int)
#define OFF_BSUM   13050257        // 256 (int)
#define OFF_BOFF   13050513        // 256 (int)
#define OFF_SRC    13050769        // NE (int)
#define OFF_DST    13850769        // NE (int)
#define OFF_ESRC   14650769        // NE (int)
#define OFF_END    15450769        // ~61.8 MB

__device__ __forceinline__ float leaky(float e) { return (e >= 0.f) ? e : NEG * e; }

// ---- edge_index ingest, robust to int32 vs int64 --------------------------
__global__ __launch_bounds__(256) void k_convert(
    const void* __restrict__ ei_raw, int* __restrict__ srcd, int* __restrict__ dstd) {
  int i = blockIdx.x * 256 + threadIdx.x;
  if (i >= 2 * NE) return;
  const unsigned long long* p64 = (const unsigned long long*)ei_raw;
  bool is64 = true;
#pragma unroll
  for (int k = 0; k < 8; ++k) is64 = is64 && (p64[k] < (unsigned long long)NN);
  int v;
  if (is64) v = (int)((const long long*)ei_raw)[i];
  else      v = ((const int*)ei_raw)[i];
  if (i < NE) srcd[i] = v;
  else        dstd[i - NE] = v;
}

// ---- h = x @ W, fused a_src = h.att_src, a_dst = h.att_dst ----------------
__global__ __launch_bounds__(256) void k_gemm(
    const float* __restrict__ x, const float* __restrict__ W,
    const float* __restrict__ attS, const float* __restrict__ attD,
    float* __restrict__ h, float* __restrict__ a_src, float* __restrict__ a_dst) {
  __shared__ float Wl[32 * NC];
  __shared__ float xl[16 * 32];
  const int t = threadIdx.x;
  const int c = t & 127;
  const int rh = t >> 7;
  const int row0 = blockIdx.x * 16;

  float acc[8];
#pragma unroll
  for (int r = 0; r < 8; ++r) acc[r] = 0.f;

  for (int k0 = 0; k0 < NC; k0 += 32) {
    __syncthreads();
    for (int i = t; i < 32 * NC; i += 256) Wl[i] = W[k0 * NC + i];
    for (int i = t; i < 16 * 32; i += 256)
      xl[i] = x[(row0 + (i >> 5)) * NC + k0 + (i & 31)];
    __syncthreads();
#pragma unroll 8
    for (int kk = 0; kk < 32; ++kk) {
      float w = Wl[kk * NC + c];
#pragma unroll
      for (int r = 0; r < 8; ++r) acc[r] += xl[(rh * 8 + r) * 32 + kk] * w;
    }
  }

  const float aS = attS[c], aD = attD[c];
#pragma unroll
  for (int r = 0; r < 8; ++r) {
    int row = row0 + rh * 8 + r;
    h[row * NC + c] = acc[r];
    float s1 = acc[r] * aS, s2 = acc[r] * aD;
    for (int off = 32; off > 0; off >>= 1) {
      s1 += __shfl_down(s1, off);
      s2 += __shfl_down(s2, off);
    }
    if ((t & 63) == 0) {
      atomicAdd(&a_src[row], s1);
      atomicAdd(&a_dst[row], s2);
    }
  }
}

// ---- CSR build ------------------------------------------------------------
__global__ __launch_bounds__(256) void k_count(
    const int* __restrict__ dstd, int* __restrict__ deg) {
  int i = blockIdx.x * 256 + threadIdx.x;
  if (i < NE) atomicAdd(&deg[dstd[i]], 1);
}

// block-local exclusive scan (Hillis-Steele in LDS), block totals to bsum
__global__ __launch_bounds__(256) void k_scan1(
    const int* __restrict__ deg, int* __restrict__ rowptr, int* __restrict__ bsum) {
  __shared__ int sh[256];
  int t = threadIdx.x, i = blockIdx.x * 256 + t;
  int v = (i < NN) ? deg[i] : 0;
  sh[t] = v;
  __syncthreads();
  for (int off = 1; off < 256; off <<= 1) {
    int x = (t >= off) ? sh[t - off] : 0;
    __syncthreads();
    sh[t] += x;
    __syncthreads();
  }
  if (i < NN) rowptr[i] = sh[t] - v;   // exclusive within block
  if (t == 255) bsum[blockIdx.x] = sh[255];
}

__global__ __launch_bounds__(256) void k_scan2(
    const int* __restrict__ bsum, int* __restrict__ boff, int nblk) {
  __shared__ int sh[256];
  int t = threadIdx.x;
  int v = (t < nblk) ? bsum[t] : 0;
  sh[t] = v;
  __syncthreads();
  for (int off = 1; off < 256; off <<= 1) {
    int x = (t >= off) ? sh[t - off] : 0;
    __syncthreads();
    sh[t] += x;
    __syncthreads();
  }
  boff[t] = sh[t] - v;                 // exclusive
}

__global__ __launch_bounds__(256) void k_scan3(
    int* __restrict__ rowptr, int* __restrict__ cursor, const int* __restrict__ boff) {
  int i = blockIdx.x * 256 + threadIdx.x;
  if (i < NN) {
    int r = rowptr[i] + boff[i >> 8];
    rowptr[i] = r;
    cursor[i] = r;
  }
  if (i == 0) rowptr[NN] = NE;
}

__global__ __launch_bounds__(256) void k_fill(
    const int* __restrict__ srcd, const int* __restrict__ dstd,
    int* __restrict__ cursor, int* __restrict__ esrc) {
  int i = blockIdx.x * 256 + threadIdx.x;
  if (i >= NE) return;
  int pos = atomicAdd(&cursor[dstd[i]], 1);
  esrc[pos] = srcd[i];
}

// ---- per-dst gather aggregation: out = softmax-weighted mean --------------
// 256 threads = 2 nodes per block; 128 threads (=2 waves) per node.
__global__ __launch_bounds__(256) void k_aggregate(
    const int* __restrict__ rowptr, const int* __restrict__ esrc,
    const float* __restrict__ a_src, const float* __restrict__ a_dst,
    const float* __restrict__ h, float* __restrict__ accum) {
  int d = blockIdx.x * 2 + (threadIdx.x >> 7);
  if (d >= NN) return;
  int c = threadIdx.x & 127;
  int beg = rowptr[d], end = rowptr[d + 1];
  float aD = a_dst[d];
  float eself = leaky(a_src[d] + aD);

  // pass 1: segment max (incl. self loop); scalar broadcast loads
  float m = eself;
  for (int j = beg; j < end; ++j)
    m = fmaxf(m, leaky(a_src[esrc[j]] + aD));

  // pass 2: fused weight-sum + weighted feature sum
  float wsum = __expf(eself - m);
  float acc = wsum * h[d * NC + c];
  for (int j = beg; j < end; ++j) {
    int s = esrc[j];
    float w = __expf(leaky(a_src[s] + aD) - m);
    wsum += w;
    acc += w * h[s * NC + c];
  }
  accum[d * NC + c] = acc / wsum;
}

// ---- per-channel sum / sumsq over nodes -----------------------------------
__global__ __launch_bounds__(256) void k_stats(
    const float* __restrict__ accum, float* __restrict__ gsum,
    float* __restrict__ gsumsq) {
  __shared__ float sh[256], sh2[256];
  int c = threadIdx.x & 127, rh = threadIdx.x >> 7;
  float s = 0.f, ss = 0.f;
  for (int row = blockIdx.x * 2 + rh; row < NN; row += gridDim.x * 2) {
    float v = accum[row * NC + c];
    s += v;
    ss += v * v;
  }
  sh[threadIdx.x] = s;
  sh2[threadIdx.x] = ss;
  __syncthreads();
  if (threadIdx.x < 128) {
    s = sh[threadIdx.x] + sh[threadIdx.x + 128];
    ss = sh2[threadIdx.x] + sh2[threadIdx.x + 128];
    atomicAdd(&gsum[c], s);
    atomicAdd(&gsumsq[c], ss);
  }
}

// ---- BatchNorm (training stats) + ReLU -> fp32 ----------------------------
__global__ __launch_bounds__(256) void k_bn(
    const float* __restrict__ accum, const float* __restrict__ gsum,
    const float* __restrict__ gsumsq, const float* __restrict__ gamma,
    const float* __restrict__ beta, float* __restrict__ out) {
  int idx = blockIdx.x * 256 + threadIdx.x;
  if (idx >= NN * NC) return;
  int c = idx & 127;
  float mean = gsum[c] * (1.0f / NN);
  float var = gsumsq[c] * (1.0f / NN) - mean * mean;
  float inv = rsqrtf(var + BN_EPS);
  float y = (accum[idx] - mean) * inv * gamma[c] + beta[c];
  out[idx] = (y > 0.f) ? y : 0.f;
}

extern "C" void kernel_launch(void* const* d_in, const int* in_sizes, int n_in,
                              void* d_out, int out_size, void* d_ws, size_t ws_size,
                              hipStream_t stream) {
  const float* x    = (const float*)d_in[0];
  const void*  ei   = d_in[1];
  // d_in[2] = edge_attr (ignored: edge_dim=None in reference)
  const float* W    = (const float*)d_in[3];
  const float* attS = (const float*)d_in[4];
  const float* attD = (const float*)d_in[5];
  // d_in[6] = bias: cancels under BN mean-subtraction (and is zeros)
  const float* gamma = (const float*)d_in[7];
  const float* beta  = (const float*)d_in[8];

  float* ws     = (float*)d_ws;
  float* h      = ws + OFF_H;
  float* accum  = ws + OFF_ACCUM;
  float* a_src  = ws + OFF_ASRC;
  float* a_dst  = ws + OFF_ADST;
  int*   deg    = (int*)(ws + OFF_DEG);
  float* gsum   = ws + OFF_GSUM;
  float* gsumsq = ws + OFF_GSUMSQ;
  int*   rowptr = (int*)(ws + OFF_ROWPTR);
  int*   cursor = (int*)(ws + OFF_CURSOR);
  int*   bsum   = (int*)(ws + OFF_BSUM);
  int*   boff   = (int*)(ws + OFF_BOFF);
  int*   srcd   = (int*)(ws + OFF_SRC);
  int*   dstd   = (int*)(ws + OFF_DST);
  int*   esrc   = (int*)(ws + OFF_ESRC);

  // zero the accumulated-into region: a_src, a_dst, deg, gsum, gsumsq
  hipMemsetAsync(a_src, 0, (size_t)(OFF_ROWPTR - OFF_ASRC) * sizeof(float), stream);

  const int nscan = (NN + 255) / 256;  // 196
  k_convert<<<(2 * NE + 255) / 256, 256, 0, stream>>>(ei, srcd, dstd);
  k_gemm<<<NN / 16, 256, 0, stream>>>(x, W, attS, attD, h, a_src, a_dst);
  k_count<<<(NE + 255) / 256, 256, 0, stream>>>(dstd, deg);
  k_scan1<<<nscan, 256, 0, stream>>>(deg, rowptr, bsum);
  k_scan2<<<1, 256, 0, stream>>>(bsum, boff, nscan);
  k_scan3<<<nscan, 256, 0, stream>>>(rowptr, cursor, boff);
  k_fill<<<(NE + 255) / 256, 256, 0, stream>>>(srcd, dstd, cursor, esrc);
  k_aggregate<<<(NN + 1) / 2, 256, 0, stream>>>(rowptr, esrc, a_src, a_dst, h, accum);
  k_stats<<<512, 256, 0, stream>>>(accum, gsum, gsumsq);
  k_bn<<<(NN * NC + 255) / 256, 256, 0, stream>>>(accum, gsum, gsumsq, gamma, beta,
                                                  (float*)d_out);
}

// Round 5
// 269.416 us; speedup vs baseline: 2.1096x; 1.5760x over previous
//
#include <hip/hip_runtime.h>
#include <hip/hip_bf16.h>

#define NN 50000
#define NE 800000
#define NC 128
#define NEG 0.2f
#define BN_EPS 1e-5f

typedef unsigned int u32;

// workspace layout (4-byte units)
#define OFF_H      0               // NN*NC floats
#define OFF_ACCUM  6400000         // NN*NC floats
#define OFF_ASRC   12800000        // NN
#define OFF_ADST   12850000        // NN
#define OFF_DEG    12900000        // NN (int)
#define OFF_GSUM   12950000        // 128
#define OFF_GSUMSQ 12950128        // 128
// ---- end of zeroed region (ASRC..GSUMSQ) ----
#define OFF_ROWPTR 12950256        // NN+1 (int)
#define OFF_CURSOR 13000257        // NN (int)
#define OFF_BSUM   13050257        // 256 (int)
#define OFF_BOFF   13050513        // 256 (int)
#define OFF_SRC    13050769        // NE (int)
#define OFF_DST    13850769        // NE (int)
#define OFF_ESRC   14650769        // NE (int)
#define OFF_END    15450769        // ~61.8 MB

__device__ __forceinline__ float leaky(float e) { return (e >= 0.f) ? e : NEG * e; }

// ---- edge_index ingest, robust to int32 vs int64 --------------------------
__global__ __launch_bounds__(256) void k_convert(
    const void* __restrict__ ei_raw, int* __restrict__ srcd, int* __restrict__ dstd) {
  int i = blockIdx.x * 256 + threadIdx.x;
  if (i >= 2 * NE) return;
  const unsigned long long* p64 = (const unsigned long long*)ei_raw;
  bool is64 = true;
#pragma unroll
  for (int k = 0; k < 8; ++k) is64 = is64 && (p64[k] < (unsigned long long)NN);
  int v;
  if (is64) v = (int)((const long long*)ei_raw)[i];
  else      v = ((const int*)ei_raw)[i];
  if (i < NE) srcd[i] = v;
  else        dstd[i - NE] = v;
}

// ---- h = x @ W, fused a_src = h.att_src, a_dst = h.att_dst ----------------
__global__ __launch_bounds__(256) void k_gemm(
    const float* __restrict__ x, const float* __restrict__ W,
    const float* __restrict__ attS, const float* __restrict__ attD,
    float* __restrict__ h, float* __restrict__ a_src, float* __restrict__ a_dst) {
  __shared__ float Wl[32 * NC];
  __shared__ float xl[16 * 32];
  const int t = threadIdx.x;
  const int c = t & 127;
  const int rh = t >> 7;
  const int row0 = blockIdx.x * 16;

  float acc[8];
#pragma unroll
  for (int r = 0; r < 8; ++r) acc[r] = 0.f;

  for (int k0 = 0; k0 < NC; k0 += 32) {
    __syncthreads();
    for (int i = t; i < 32 * NC; i += 256) Wl[i] = W[k0 * NC + i];
    for (int i = t; i < 16 * 32; i += 256)
      xl[i] = x[(row0 + (i >> 5)) * NC + k0 + (i & 31)];
    __syncthreads();
#pragma unroll 8
    for (int kk = 0; kk < 32; ++kk) {
      float w = Wl[kk * NC + c];
#pragma unroll
      for (int r = 0; r < 8; ++r) acc[r] += xl[(rh * 8 + r) * 32 + kk] * w;
    }
  }

  const float aS = attS[c], aD = attD[c];
#pragma unroll
  for (int r = 0; r < 8; ++r) {
    int row = row0 + rh * 8 + r;
    h[row * NC + c] = acc[r];
    float s1 = acc[r] * aS, s2 = acc[r] * aD;
    for (int off = 32; off > 0; off >>= 1) {
      s1 += __shfl_down(s1, off);
      s2 += __shfl_down(s2, off);
    }
    if ((t & 63) == 0) {
      atomicAdd(&a_src[row], s1);
      atomicAdd(&a_dst[row], s2);
    }
  }
}

// ---- CSR build ------------------------------------------------------------
__global__ __launch_bounds__(256) void k_count(
    const int* __restrict__ dstd, int* __restrict__ deg) {
  int i = blockIdx.x * 256 + threadIdx.x;
  if (i < NE) atomicAdd(&deg[dstd[i]], 1);
}

__global__ __launch_bounds__(256) void k_scan1(
    const int* __restrict__ deg, int* __restrict__ rowptr, int* __restrict__ bsum) {
  __shared__ int sh[256];
  int t = threadIdx.x, i = blockIdx.x * 256 + t;
  int v = (i < NN) ? deg[i] : 0;
  sh[t] = v;
  __syncthreads();
  for (int off = 1; off < 256; off <<= 1) {
    int x = (t >= off) ? sh[t - off] : 0;
    __syncthreads();
    sh[t] += x;
    __syncthreads();
  }
  if (i < NN) rowptr[i] = sh[t] - v;
  if (t == 255) bsum[blockIdx.x] = sh[255];
}

__global__ __launch_bounds__(256) void k_scan2(
    const int* __restrict__ bsum, int* __restrict__ boff, int nblk) {
  __shared__ int sh[256];
  int t = threadIdx.x;
  int v = (t < nblk) ? bsum[t] : 0;
  sh[t] = v;
  __syncthreads();
  for (int off = 1; off < 256; off <<= 1) {
    int x = (t >= off) ? sh[t - off] : 0;
    __syncthreads();
    sh[t] += x;
    __syncthreads();
  }
  boff[t] = sh[t] - v;
}

__global__ __launch_bounds__(256) void k_scan3(
    int* __restrict__ rowptr, int* __restrict__ cursor, const int* __restrict__ boff) {
  int i = blockIdx.x * 256 + threadIdx.x;
  if (i < NN) {
    int r = rowptr[i] + boff[i >> 8];
    rowptr[i] = r;
    cursor[i] = r;
  }
  if (i == 0) rowptr[NN] = NE;
}

__global__ __launch_bounds__(256) void k_fill(
    const int* __restrict__ srcd, const int* __restrict__ dstd,
    int* __restrict__ cursor, int* __restrict__ esrc) {
  int i = blockIdx.x * 256 + threadIdx.x;
  if (i >= NE) return;
  int pos = atomicAdd(&cursor[dstd[i]], 1);
  esrc[pos] = srcd[i];
}

// ---- per-dst gather aggregation, wave-per-node, shuffle-broadcast ---------
// softmax without max-subtraction (shift-invariant; |e| <= ~8 so exp is safe)
__global__ __launch_bounds__(256) void k_aggregate(
    const int* __restrict__ rowptr, const int* __restrict__ esrc,
    const float* __restrict__ a_src, const float* __restrict__ a_dst,
    const float* __restrict__ h, float* __restrict__ accum) {
  int d = blockIdx.x * 4 + (threadIdx.x >> 6);
  if (d >= NN) return;
  int l = threadIdx.x & 63;            // lane: owns channels 2l, 2l+1
  int beg = rowptr[d], end = rowptr[d + 1];
  float aD = a_dst[d];

  float2 acc = make_float2(0.f, 0.f);
  float wpart = 0.f;

  for (int j0 = beg; j0 < end; j0 += 64) {
    int n = min(64, end - j0);
    int s = 0;
    float w = 0.f;
    if (l < n) {
      s = esrc[j0 + l];
      w = __expf(leaky(a_src[s] + aD));
      wpart += w;
    }
    for (int jj = 0; jj < n; ++jj) {
      int sj = __shfl(s, jj);
      float wj = __shfl(w, jj);
      const float2 hv = *(const float2*)&h[sj * NC + 2 * l];
      acc.x += wj * hv.x;
      acc.y += wj * hv.y;
    }
  }

  // reduce wsum across the wave
  for (int off = 32; off > 0; off >>= 1) wpart += __shfl_xor(wpart, off);

  // self loop
  float wself = __expf(leaky(a_src[d] + aD));
  const float2 hd = *(const float2*)&h[d * NC + 2 * l];
  acc.x += wself * hd.x;
  acc.y += wself * hd.y;

  float inv = 1.f / (wpart + wself);
  *(float2*)&accum[d * NC + 2 * l] = make_float2(acc.x * inv, acc.y * inv);
}

// ---- per-channel sum / sumsq over nodes -----------------------------------
__global__ __launch_bounds__(256) void k_stats(
    const float* __restrict__ accum, float* __restrict__ gsum,
    float* __restrict__ gsumsq) {
  __shared__ float sh[256], sh2[256];
  int c = threadIdx.x & 127, rh = threadIdx.x >> 7;
  float s = 0.f, ss = 0.f;
  for (int row = blockIdx.x * 2 + rh; row < NN; row += gridDim.x * 2) {
    float v = accum[row * NC + c];
    s += v;
    ss += v * v;
  }
  sh[threadIdx.x] = s;
  sh2[threadIdx.x] = ss;
  __syncthreads();
  if (threadIdx.x < 128) {
    s = sh[threadIdx.x] + sh[threadIdx.x + 128];
    ss = sh2[threadIdx.x] + sh2[threadIdx.x + 128];
    atomicAdd(&gsum[c], s);
    atomicAdd(&gsumsq[c], ss);
  }
}

// ---- BatchNorm (training stats) + ReLU -> fp32 ----------------------------
__global__ __launch_bounds__(256) void k_bn(
    const float* __restrict__ accum, const float* __restrict__ gsum,
    const float* __restrict__ gsumsq, const float* __restrict__ gamma,
    const float* __restrict__ beta, float* __restrict__ out) {
  int idx = blockIdx.x * 256 + threadIdx.x;
  if (idx >= NN * NC) return;
  int c = idx & 127;
  float mean = gsum[c] * (1.0f / NN);
  float var = gsumsq[c] * (1.0f / NN) - mean * mean;
  float inv = rsqrtf(var + BN_EPS);
  float y = (accum[idx] - mean) * inv * gamma[c] + beta[c];
  out[idx] = (y > 0.f) ? y : 0.f;
}

extern "C" void kernel_launch(void* const* d_in, const int* in_sizes, int n_in,
                              void* d_out, int out_size, void* d_ws, size_t ws_size,
                              hipStream_t stream) {
  const float* x    = (const float*)d_in[0];
  const void*  ei   = d_in[1];
  // d_in[2] = edge_attr (ignored: edge_dim=None in reference)
  const float* W    = (const float*)d_in[3];
  const float* attS = (const float*)d_in[4];
  const float* attD = (const float*)d_in[5];
  // d_in[6] = bias: cancels under BN mean-subtraction (and is zeros)
  const float* gamma = (const float*)d_in[7];
  const float* beta  = (const float*)d_in[8];

  float* ws     = (float*)d_ws;
  float* h      = ws + OFF_H;
  float* accum  = ws + OFF_ACCUM;
  float* a_src  = ws + OFF_ASRC;
  float* a_dst  = ws + OFF_ADST;
  int*   deg    = (int*)(ws + OFF_DEG);
  float* gsum   = ws + OFF_GSUM;
  float* gsumsq = ws + OFF_GSUMSQ;
  int*   rowptr = (int*)(ws + OFF_ROWPTR);
  int*   cursor = (int*)(ws + OFF_CURSOR);
  int*   bsum   = (int*)(ws + OFF_BSUM);
  int*   boff   = (int*)(ws + OFF_BOFF);
  int*   srcd   = (int*)(ws + OFF_SRC);
  int*   dstd   = (int*)(ws + OFF_DST);
  int*   esrc   = (int*)(ws + OFF_ESRC);

  // zero the accumulated-into region: a_src, a_dst, deg, gsum, gsumsq
  hipMemsetAsync(a_src, 0, (size_t)(OFF_ROWPTR - OFF_ASRC) * sizeof(float), stream);

  const int nscan = (NN + 255) / 256;  // 196
  k_convert<<<(2 * NE + 255) / 256, 256, 0, stream>>>(ei, srcd, dstd);
  k_gemm<<<NN / 16, 256, 0, stream>>>(x, W, attS, attD, h, a_src, a_dst);
  k_count<<<(NE + 255) / 256, 256, 0, stream>>>(dstd, deg);
  k_scan1<<<nscan, 256, 0, stream>>>(deg, rowptr, bsum);
  k_scan2<<<1, 256, 0, stream>>>(bsum, boff, nscan);
  k_scan3<<<nscan, 256, 0, stream>>>(rowptr, cursor, boff);
  k_fill<<<(NE + 255) / 256, 256, 0, stream>>>(srcd, dstd, cursor, esrc);
  k_aggregate<<<(NN + 3) / 4, 256, 0, stream>>>(rowptr, esrc, a_src, a_dst, h, accum);
  k_stats<<<512, 256, 0, stream>>>(accum, gsum, gsumsq);
  k_bn<<<(NN * NC + 255) / 256, 256, 0, stream>>>(accum, gsum, gsumsq, gamma, beta,
                                                  (float*)d_out);
}

// Round 6
// 237.134 us; speedup vs baseline: 2.3968x; 1.1361x over previous
//
#include <hip/hip_runtime.h>
#include <hip/hip_bf16.h>

#define NN 50000
#define NE 800000
#define NC 128
#define NEG 0.2f
#define BN_EPS 1e-5f

typedef unsigned int u32;
typedef unsigned short u16;
typedef short bf16x8 __attribute__((ext_vector_type(8)));
typedef float f32x4 __attribute__((ext_vector_type(4)));

// workspace layout (4-byte units)
#define OFF_H      0               // NN*NC bf16 (3.2M u32 units)
#define OFF_ACCUM  3200000         // NN*NC floats
#define OFF_ASRC   9600000         // NN
#define OFF_ADST   9650000         // NN
#define OFF_DEG    9700000         // NN (int)      <- zeroed from here
#define OFF_GSUM   9750000         // 128
#define OFF_GSUMSQ 9750128         // 128           <- zeroed to here
#define OFF_ROWPTR 9750256         // NN+1 (int)
#define OFF_CURSOR 9800257         // NN (int)
#define OFF_BSUM   9850257         // 256 (int)
#define OFF_BOFF   9850513         // 256 (int)
#define OFF_SRC    9850769         // NE (int)
#define OFF_DST    10650769        // NE (int)
#define OFF_ESRC   11450769        // NE (int)
#define OFF_END    12250769        // ~49 MB

__device__ __forceinline__ float leaky(float e) { return (e >= 0.f) ? e : NEG * e; }

__device__ __forceinline__ u16 f2b(float f) {   // fp32 -> bf16 RNE
  union { float f; u32 u; } v; v.f = f;
  u32 u = v.u;
  return (u16)((u + 0x7fffu + ((u >> 16) & 1u)) >> 16);
}
__device__ __forceinline__ float b2f(u16 b) {
  union { u32 u; float f; } v; v.u = ((u32)b) << 16;
  return v.f;
}

// ---- edge ingest (int32/int64 robust) + degree count ----------------------
__global__ __launch_bounds__(256) void k_convert(
    const void* __restrict__ ei_raw, int* __restrict__ srcd,
    int* __restrict__ dstd, int* __restrict__ deg) {
  int i = blockIdx.x * 256 + threadIdx.x;
  if (i >= 2 * NE) return;
  const unsigned long long* p64 = (const unsigned long long*)ei_raw;
  bool is64 = true;
#pragma unroll
  for (int k = 0; k < 8; ++k) is64 = is64 && (p64[k] < (unsigned long long)NN);
  int v;
  if (is64) v = (int)((const long long*)ei_raw)[i];
  else      v = ((const int*)ei_raw)[i];
  if (i < NE) srcd[i] = v;
  else { dstd[i - NE] = v; atomicAdd(&deg[v], 1); }
}

// ---- h = x@W via MFMA bf16; fused a_src/a_dst; h stored bf16 --------------
// block = 256 thr = 4 waves; wave w handles rows r0 = bid*64 + w*16 (all 128 cols, full K).
// W staged to LDS transposed (Wt[col][k], bf16), XOR-swizzled 16B blocks by (col&7).
__global__ __launch_bounds__(256) void k_gemm(
    const float* __restrict__ x, const float* __restrict__ W,
    const float* __restrict__ attS, const float* __restrict__ attD,
    u16* __restrict__ h, float* __restrict__ a_src, float* __restrict__ a_dst) {
  __shared__ u16 Wt[NC * NC];      // 32 KB
  const int t = threadIdx.x;
  const int l = t & 63;
  const int r0 = blockIdx.x * 64 + (t >> 6) * 16;

  // stage W -> LDS: iter j: lanes 0..63 fill one col's 256B row (conflict-free writes)
  for (int p = t; p < 8192; p += 256) {
    int col = p >> 6;
    int k = (p & 63) * 2;                       // k, k+1 pair
    float w0 = W[k * NC + col];
    float w1 = W[(k + 1) * NC + col];
    u32 packed = ((u32)f2b(w1) << 16) | f2b(w0);
    int byte = col * 256 + ((k * 2) ^ ((col & 7) << 4));
    *(u32*)((char*)Wt + byte) = packed;
  }
  __syncthreads();

  const int arow = r0 + (l & 15);               // A-fragment row
  const bool aok = arow < NN;
  const int kg = l >> 4;                        // k-group 0..3
  const float* xa = x + (size_t)arow * NC + kg * 8;

  f32x4 acc[8];
#pragma unroll
  for (int n = 0; n < 8; ++n) acc[n] = (f32x4){0.f, 0.f, 0.f, 0.f};

  // per-lane LDS byte base for B fragments: col = 16n + (l&15)
  const int bbase = (l & 15) * 256;

#pragma unroll
  for (int s = 0; s < 4; ++s) {
    // A fragment: 8 fp32 -> bf16
    f32x4 a0 = (f32x4){0.f,0.f,0.f,0.f}, a1 = a0;
    if (aok) {
      a0 = *(const f32x4*)(xa + s * 32);
      a1 = *(const f32x4*)(xa + s * 32 + 4);
    }
    bf16x8 af;
    af[0]=(short)f2b(a0[0]); af[1]=(short)f2b(a0[1]);
    af[2]=(short)f2b(a0[2]); af[3]=(short)f2b(a0[3]);
    af[4]=(short)f2b(a1[0]); af[5]=(short)f2b(a1[1]);
    af[6]=(short)f2b(a1[2]); af[7]=(short)f2b(a1[3]);

    int kb2 = 16 * (s * 4 + kg);                // byte offset of 8-k slice
    int boff = bbase + (kb2 ^ ((l & 7) << 4));
#pragma unroll
    for (int n = 0; n < 8; ++n) {
      bf16x8 bf = *(const bf16x8*)((const char*)Wt + boff + n * 4096);
      acc[n] = __builtin_amdgcn_mfma_f32_16x16x32_bf16(af, bf, acc[n], 0, 0, 0);
    }
  }

  // epilogue: h (bf16) + per-row attention logits (no atomics: full K in-block)
  float attS_r[8], attD_r[8];
#pragma unroll
  for (int n = 0; n < 8; ++n) {
    attS_r[n] = attS[16 * n + (l & 15)];
    attD_r[n] = attD[16 * n + (l & 15)];
  }
#pragma unroll
  for (int q = 0; q < 4; ++q) {
    int row = r0 + kg * 4 + q;
    bool rok = row < NN;
    float sA = 0.f, sD = 0.f;
#pragma unroll
    for (int n = 0; n < 8; ++n) {
      float v = acc[n][q];
      sA += v * attS_r[n];
      sD += v * attD_r[n];
      if (rok) h[(size_t)row * NC + 16 * n + (l & 15)] = f2b(v);
    }
    sA += __shfl_xor(sA, 1); sD += __shfl_xor(sD, 1);
    sA += __shfl_xor(sA, 2); sD += __shfl_xor(sD, 2);
    sA += __shfl_xor(sA, 4); sD += __shfl_xor(sD, 4);
    sA += __shfl_xor(sA, 8); sD += __shfl_xor(sD, 8);
    if ((l & 15) == 0 && rok) { a_src[row] = sA; a_dst[row] = sD; }
  }
}

// ---- CSR scan -------------------------------------------------------------
__global__ __launch_bounds__(256) void k_scan1(
    const int* __restrict__ deg, int* __restrict__ rowptr, int* __restrict__ bsum) {
  __shared__ int sh[256];
  int t = threadIdx.x, i = blockIdx.x * 256 + t;
  int v = (i < NN) ? deg[i] : 0;
  sh[t] = v;
  __syncthreads();
  for (int off = 1; off < 256; off <<= 1) {
    int xv = (t >= off) ? sh[t - off] : 0;
    __syncthreads();
    sh[t] += xv;
    __syncthreads();
  }
  if (i < NN) rowptr[i] = sh[t] - v;
  if (t == 255) bsum[blockIdx.x] = sh[255];
}

__global__ __launch_bounds__(256) void k_scan2(
    const int* __restrict__ bsum, int* __restrict__ boff, int nblk) {
  __shared__ int sh[256];
  int t = threadIdx.x;
  int v = (t < nblk) ? bsum[t] : 0;
  sh[t] = v;
  __syncthreads();
  for (int off = 1; off < 256; off <<= 1) {
    int xv = (t >= off) ? sh[t - off] : 0;
    __syncthreads();
    sh[t] += xv;
    __syncthreads();
  }
  boff[t] = sh[t] - v;
}

__global__ __launch_bounds__(256) void k_scan3(
    int* __restrict__ rowptr, int* __restrict__ cursor, const int* __restrict__ boff) {
  int i = blockIdx.x * 256 + threadIdx.x;
  if (i < NN) {
    int r = rowptr[i] + boff[i >> 8];
    rowptr[i] = r;
    cursor[i] = r;
  }
  if (i == 0) rowptr[NN] = NE;
}

__global__ __launch_bounds__(256) void k_fill(
    const int* __restrict__ srcd, const int* __restrict__ dstd,
    int* __restrict__ cursor, int* __restrict__ esrc) {
  int i = blockIdx.x * 256 + threadIdx.x;
  if (i >= NE) return;
  int pos = atomicAdd(&cursor[dstd[i]], 1);
  esrc[pos] = srcd[i];
}

// ---- per-dst gather aggregation, wave-per-node, shuffle-broadcast ---------
__global__ __launch_bounds__(256) void k_aggregate(
    const int* __restrict__ rowptr, const int* __restrict__ esrc,
    const float* __restrict__ a_src, const float* __restrict__ a_dst,
    const u16* __restrict__ h, float* __restrict__ accum) {
  int d = blockIdx.x * 4 + (threadIdx.x >> 6);
  if (d >= NN) return;
  int l = threadIdx.x & 63;            // lane owns channels 2l, 2l+1
  int beg = rowptr[d], end = rowptr[d + 1];
  float aD = a_dst[d];

  float2 acc = make_float2(0.f, 0.f);
  float wpart = 0.f;

  for (int j0 = beg; j0 < end; j0 += 64) {
    int n = min(64, end - j0);
    int s = 0;
    float w = 0.f;
    if (l < n) {
      s = esrc[j0 + l];
      w = __expf(leaky(a_src[s] + aD));
      wpart += w;
    }
    for (int jj = 0; jj < n; ++jj) {
      int sj = __shfl(s, jj);
      float wj = __shfl(w, jj);
      u32 hw = *(const u32*)&h[(size_t)sj * NC + 2 * l];
      union { u32 u; float f; } lo, hi;
      lo.u = hw << 16; hi.u = hw & 0xffff0000u;
      acc.x += wj * lo.f;
      acc.y += wj * hi.f;
    }
  }

  for (int off = 32; off > 0; off >>= 1) wpart += __shfl_xor(wpart, off);

  // self loop
  float wself = __expf(leaky(a_src[d] + aD));
  u32 hw = *(const u32*)&h[(size_t)d * NC + 2 * l];
  union { u32 u; float f; } lo, hi;
  lo.u = hw << 16; hi.u = hw & 0xffff0000u;
  acc.x += wself * lo.f;
  acc.y += wself * hi.f;

  float inv = 1.f / (wpart + wself);
  *(float2*)&accum[(size_t)d * NC + 2 * l] = make_float2(acc.x * inv, acc.y * inv);
}

// ---- per-channel sum / sumsq ----------------------------------------------
__global__ __launch_bounds__(256) void k_stats(
    const float* __restrict__ accum, float* __restrict__ gsum,
    float* __restrict__ gsumsq) {
  __shared__ float sh[256], sh2[256];
  int c = threadIdx.x & 127, rh = threadIdx.x >> 7;
  float s = 0.f, ss = 0.f;
  for (int row = blockIdx.x * 2 + rh; row < NN; row += gridDim.x * 2) {
    float v = accum[row * NC + c];
    s += v;
    ss += v * v;
  }
  sh[threadIdx.x] = s;
  sh2[threadIdx.x] = ss;
  __syncthreads();
  if (threadIdx.x < 128) {
    s = sh[threadIdx.x] + sh[threadIdx.x + 128];
    ss = sh2[threadIdx.x] + sh2[threadIdx.x + 128];
    atomicAdd(&gsum[c], s);
    atomicAdd(&gsumsq[c], ss);
  }
}

// ---- BatchNorm (training stats) + ReLU -> fp32 ----------------------------
__global__ __launch_bounds__(256) void k_bn(
    const float* __restrict__ accum, const float* __restrict__ gsum,
    const float* __restrict__ gsumsq, const float* __restrict__ gamma,
    const float* __restrict__ beta, float* __restrict__ out) {
  int idx = blockIdx.x * 256 + threadIdx.x;
  if (idx >= NN * NC) return;
  int c = idx & 127;
  float mean = gsum[c] * (1.0f / NN);
  float var = gsumsq[c] * (1.0f / NN) - mean * mean;
  float inv = rsqrtf(var + BN_EPS);
  float y = (accum[idx] - mean) * inv * gamma[c] + beta[c];
  out[idx] = (y > 0.f) ? y : 0.f;
}

extern "C" void kernel_launch(void* const* d_in, const int* in_sizes, int n_in,
                              void* d_out, int out_size, void* d_ws, size_t ws_size,
                              hipStream_t stream) {
  const float* x    = (const float*)d_in[0];
  const void*  ei   = d_in[1];
  // d_in[2] = edge_attr (ignored: edge_dim=None in reference)
  const float* W    = (const float*)d_in[3];
  const float* attS = (const float*)d_in[4];
  const float* attD = (const float*)d_in[5];
  // d_in[6] = bias: cancels under BN mean-subtraction (and is zeros)
  const float* gamma = (const float*)d_in[7];
  const float* beta  = (const float*)d_in[8];

  float* ws     = (float*)d_ws;
  u16*   h      = (u16*)(ws + OFF_H);
  float* accum  = ws + OFF_ACCUM;
  float* a_src  = ws + OFF_ASRC;
  float* a_dst  = ws + OFF_ADST;
  int*   deg    = (int*)(ws + OFF_DEG);
  float* gsum   = ws + OFF_GSUM;
  float* gsumsq = ws + OFF_GSUMSQ;
  int*   rowptr = (int*)(ws + OFF_ROWPTR);
  int*   cursor = (int*)(ws + OFF_CURSOR);
  int*   bsum   = (int*)(ws + OFF_BSUM);
  int*   boff   = (int*)(ws + OFF_BOFF);
  int*   srcd   = (int*)(ws + OFF_SRC);
  int*   dstd   = (int*)(ws + OFF_DST);
  int*   esrc   = (int*)(ws + OFF_ESRC);

  // zero deg + gsum + gsumsq
  hipMemsetAsync(deg, 0, (size_t)(OFF_ROWPTR - OFF_DEG) * sizeof(float), stream);

  const int nscan = (NN + 255) / 256;  // 196
  k_convert<<<(2 * NE + 255) / 256, 256, 0, stream>>>(ei, srcd, dstd, deg);
  k_gemm<<<(NN + 63) / 64, 256, 0, stream>>>(x, W, attS, attD, h, a_src, a_dst);
  k_scan1<<<nscan, 256, 0, stream>>>(deg, rowptr, bsum);
  k_scan2<<<1, 256, 0, stream>>>(bsum, boff, nscan);
  k_scan3<<<nscan, 256, 0, stream>>>(rowptr, cursor, boff);
  k_fill<<<(NE + 255) / 256, 256, 0, stream>>>(srcd, dstd, cursor, esrc);
  k_aggregate<<<(NN + 3) / 4, 256, 0, stream>>>(rowptr, esrc, a_src, a_dst, h, accum);
  k_stats<<<512, 256, 0, stream>>>(accum, gsum, gsumsq);
  k_bn<<<(NN * NC + 255) / 256, 256, 0, stream>>>(accum, gsum, gsumsq, gamma, beta,
                                                  (float*)d_out);
}

// Round 7
// 219.204 us; speedup vs baseline: 2.5928x; 1.0818x over previous
//
#include <hip/hip_runtime.h>
#include <hip/hip_bf16.h>

#define NN 50000
#define NE 800000
#define NC 128
#define NEG 0.2f
#define BN_EPS 1e-5f

typedef unsigned int u32;
typedef unsigned short u16;
typedef short bf16x8 __attribute__((ext_vector_type(8)));
typedef float f32x4 __attribute__((ext_vector_type(4)));

// workspace layout (4-byte units)
#define OFF_H      0               // NN*NC bf16 (3.2M u32 units)
#define OFF_ACCUM  3200000         // NN*NC floats
#define OFF_ASRC   9600000         // NN
#define OFF_ADST   9650000         // NN
#define OFF_DEG    9700000         // NN (int)      <- zeroed from here
#define OFF_GSUM   9750000         // 128
#define OFF_GSUMSQ 9750128         // 128           <- zeroed to here
#define OFF_ROWPTR 9750256         // NN+1 (int)
#define OFF_CURSOR 9800257         // NN (int)
#define OFF_BSUM   9850257         // 256 (int)
#define OFF_BOFF   9850513         // 256 (int)
#define OFF_ESRC   9850769         // NE (int)
#define OFF_END    10650769       // ~42.6 MB

__device__ __forceinline__ float leaky(float e) { return (e >= 0.f) ? e : NEG * e; }

__device__ __forceinline__ u16 f2b(float f) {   // fp32 -> bf16 RNE
  union { float f; u32 u; } v; v.f = f;
  u32 u = v.u;
  return (u16)((u + 0x7fffu + ((u >> 16) & 1u)) >> 16);
}
__device__ __forceinline__ float blo(u32 u) {
  union { u32 u; float f; } v; v.u = u << 16; return v.f;
}
__device__ __forceinline__ float bhi(u32 u) {
  union { u32 u; float f; } v; v.u = u & 0xffff0000u; return v.f;
}

__device__ __forceinline__ bool ei_is64(const void* ei_raw) {
  const unsigned long long* p64 = (const unsigned long long*)ei_raw;
  bool is64 = true;
#pragma unroll
  for (int k = 0; k < 8; ++k) is64 = is64 && (p64[k] < (unsigned long long)NN);
  return is64;
}

// ---- degree count straight from raw edge buffer ---------------------------
__global__ __launch_bounds__(256) void k_deg(
    const void* __restrict__ ei_raw, int* __restrict__ deg) {
  int i = blockIdx.x * 256 + threadIdx.x;
  if (i >= NE) return;
  int d;
  if (ei_is64(ei_raw)) d = (int)((const long long*)ei_raw)[NE + i];
  else                 d = ((const int*)ei_raw)[NE + i];
  atomicAdd(&deg[d], 1);
}

// ---- h = x@W via MFMA bf16; fused a_src/a_dst; h stored bf16 --------------
__global__ __launch_bounds__(256) void k_gemm(
    const float* __restrict__ x, const float* __restrict__ W,
    const float* __restrict__ attS, const float* __restrict__ attD,
    u16* __restrict__ h, float* __restrict__ a_src, float* __restrict__ a_dst) {
  __shared__ u16 Wt[NC * NC];      // 32 KB
  const int t = threadIdx.x;
  const int l = t & 63;
  const int r0 = blockIdx.x * 64 + (t >> 6) * 16;

  for (int p = t; p < 8192; p += 256) {
    int col = p >> 6;
    int k = (p & 63) * 2;
    float w0 = W[k * NC + col];
    float w1 = W[(k + 1) * NC + col];
    u32 packed = ((u32)f2b(w1) << 16) | f2b(w0);
    int byte = col * 256 + ((k * 2) ^ ((col & 7) << 4));
    *(u32*)((char*)Wt + byte) = packed;
  }
  __syncthreads();

  const int arow = r0 + (l & 15);
  const bool aok = arow < NN;
  const int kg = l >> 4;
  const float* xa = x + (size_t)arow * NC + kg * 8;

  f32x4 acc[8];
#pragma unroll
  for (int n = 0; n < 8; ++n) acc[n] = (f32x4){0.f, 0.f, 0.f, 0.f};

  const int bbase = (l & 15) * 256;

#pragma unroll
  for (int s = 0; s < 4; ++s) {
    f32x4 a0 = (f32x4){0.f,0.f,0.f,0.f}, a1 = a0;
    if (aok) {
      a0 = *(const f32x4*)(xa + s * 32);
      a1 = *(const f32x4*)(xa + s * 32 + 4);
    }
    bf16x8 af;
    af[0]=(short)f2b(a0[0]); af[1]=(short)f2b(a0[1]);
    af[2]=(short)f2b(a0[2]); af[3]=(short)f2b(a0[3]);
    af[4]=(short)f2b(a1[0]); af[5]=(short)f2b(a1[1]);
    af[6]=(short)f2b(a1[2]); af[7]=(short)f2b(a1[3]);

    int kb2 = 16 * (s * 4 + kg);
    int boff = bbase + (kb2 ^ ((l & 7) << 4));
#pragma unroll
    for (int n = 0; n < 8; ++n) {
      bf16x8 bf = *(const bf16x8*)((const char*)Wt + boff + n * 4096);
      acc[n] = __builtin_amdgcn_mfma_f32_16x16x32_bf16(af, bf, acc[n], 0, 0, 0);
    }
  }

  float attS_r[8], attD_r[8];
#pragma unroll
  for (int n = 0; n < 8; ++n) {
    attS_r[n] = attS[16 * n + (l & 15)];
    attD_r[n] = attD[16 * n + (l & 15)];
  }
#pragma unroll
  for (int q = 0; q < 4; ++q) {
    int row = r0 + kg * 4 + q;
    bool rok = row < NN;
    float sA = 0.f, sD = 0.f;
#pragma unroll
    for (int n = 0; n < 8; ++n) {
      float v = acc[n][q];
      sA += v * attS_r[n];
      sD += v * attD_r[n];
      if (rok) h[(size_t)row * NC + 16 * n + (l & 15)] = f2b(v);
    }
    sA += __shfl_xor(sA, 1); sD += __shfl_xor(sD, 1);
    sA += __shfl_xor(sA, 2); sD += __shfl_xor(sD, 2);
    sA += __shfl_xor(sA, 4); sD += __shfl_xor(sD, 4);
    sA += __shfl_xor(sA, 8); sD += __shfl_xor(sD, 8);
    if ((l & 15) == 0 && rok) { a_src[row] = sA; a_dst[row] = sD; }
  }
}

// ---- CSR scan -------------------------------------------------------------
__global__ __launch_bounds__(256) void k_scan1(
    const int* __restrict__ deg, int* __restrict__ rowptr, int* __restrict__ bsum) {
  __shared__ int sh[256];
  int t = threadIdx.x, i = blockIdx.x * 256 + t;
  int v = (i < NN) ? deg[i] : 0;
  sh[t] = v;
  __syncthreads();
  for (int off = 1; off < 256; off <<= 1) {
    int xv = (t >= off) ? sh[t - off] : 0;
    __syncthreads();
    sh[t] += xv;
    __syncthreads();
  }
  if (i < NN) rowptr[i] = sh[t] - v;
  if (t == 255) bsum[blockIdx.x] = sh[255];
}

__global__ __launch_bounds__(256) void k_scan2(
    const int* __restrict__ bsum, int* __restrict__ boff, int nblk) {
  __shared__ int sh[256];
  int t = threadIdx.x;
  int v = (t < nblk) ? bsum[t] : 0;
  sh[t] = v;
  __syncthreads();
  for (int off = 1; off < 256; off <<= 1) {
    int xv = (t >= off) ? sh[t - off] : 0;
    __syncthreads();
    sh[t] += xv;
    __syncthreads();
  }
  boff[t] = sh[t] - v;
}

__global__ __launch_bounds__(256) void k_scan3(
    int* __restrict__ rowptr, int* __restrict__ cursor, const int* __restrict__ boff) {
  int i = blockIdx.x * 256 + threadIdx.x;
  if (i < NN) {
    int r = rowptr[i] + boff[i >> 8];
    rowptr[i] = r;
    cursor[i] = r;
  }
  if (i == 0) rowptr[NN] = NE;
}

// ---- CSR fill straight from raw edge buffer -------------------------------
__global__ __launch_bounds__(256) void k_fill(
    const void* __restrict__ ei_raw, int* __restrict__ cursor,
    int* __restrict__ esrc) {
  int i = blockIdx.x * 256 + threadIdx.x;
  if (i >= NE) return;
  int s, d;
  if (ei_is64(ei_raw)) {
    s = (int)((const long long*)ei_raw)[i];
    d = (int)((const long long*)ei_raw)[NE + i];
  } else {
    s = ((const int*)ei_raw)[i];
    d = ((const int*)ei_raw)[NE + i];
  }
  int pos = atomicAdd(&cursor[d], 1);
  esrc[pos] = s;
}

// ---- per-dst gather, wave-per-node, 4-way-unrolled shuffle-broadcast ------
__global__ __launch_bounds__(256) void k_aggregate(
    const int* __restrict__ rowptr, const int* __restrict__ esrc,
    const float* __restrict__ a_src, const float* __restrict__ a_dst,
    const u16* __restrict__ h, float* __restrict__ accum) {
  int d = blockIdx.x * 4 + (threadIdx.x >> 6);
  if (d >= NN) return;
  int l = threadIdx.x & 63;            // lane owns channels 2l, 2l+1
  int beg = rowptr[d], end = rowptr[d + 1];
  float aD = a_dst[d];

  float2 ac0 = make_float2(0.f, 0.f), ac1 = ac0, ac2 = ac0, ac3 = ac0;
  float wpart = 0.f;

  for (int j0 = beg; j0 < end; j0 += 64) {
    int n = min(64, end - j0);
    int s = 0;
    float w = 0.f;
    if (l < n) {
      s = esrc[j0 + l];
      w = __expf(leaky(a_src[s] + aD));
      wpart += w;
    }
    int jj = 0;
    for (; jj + 4 <= n; jj += 4) {
      int s0 = __shfl(s, jj),     s1 = __shfl(s, jj + 1);
      int s2 = __shfl(s, jj + 2), s3 = __shfl(s, jj + 3);
      float w0 = __shfl(w, jj),     w1 = __shfl(w, jj + 1);
      float w2 = __shfl(w, jj + 2), w3 = __shfl(w, jj + 3);
      u32 h0 = *(const u32*)&h[(size_t)s0 * NC + 2 * l];
      u32 h1 = *(const u32*)&h[(size_t)s1 * NC + 2 * l];
      u32 h2 = *(const u32*)&h[(size_t)s2 * NC + 2 * l];
      u32 h3 = *(const u32*)&h[(size_t)s3 * NC + 2 * l];
      ac0.x += w0 * blo(h0); ac0.y += w0 * bhi(h0);
      ac1.x += w1 * blo(h1); ac1.y += w1 * bhi(h1);
      ac2.x += w2 * blo(h2); ac2.y += w2 * bhi(h2);
      ac3.x += w3 * blo(h3); ac3.y += w3 * bhi(h3);
    }
    for (; jj < n; ++jj) {
      int sj = __shfl(s, jj);
      float wj = __shfl(w, jj);
      u32 hw = *(const u32*)&h[(size_t)sj * NC + 2 * l];
      ac0.x += wj * blo(hw); ac0.y += wj * bhi(hw);
    }
  }

  for (int off = 32; off > 0; off >>= 1) wpart += __shfl_xor(wpart, off);

  // self loop
  float wself = __expf(leaky(a_src[d] + aD));
  u32 hw = *(const u32*)&h[(size_t)d * NC + 2 * l];
  float accx = ac0.x + ac1.x + ac2.x + ac3.x + wself * blo(hw);
  float accy = ac0.y + ac1.y + ac2.y + ac3.y + wself * bhi(hw);

  float inv = 1.f / (wpart + wself);
  *(float2*)&accum[(size_t)d * NC + 2 * l] = make_float2(accx * inv, accy * inv);
}

// ---- per-channel sum / sumsq ----------------------------------------------
__global__ __launch_bounds__(256) void k_stats(
    const float* __restrict__ accum, float* __restrict__ gsum,
    float* __restrict__ gsumsq) {
  __shared__ float sh[256], sh2[256];
  int c = threadIdx.x & 127, rh = threadIdx.x >> 7;
  float s = 0.f, ss = 0.f;
  for (int row = blockIdx.x * 2 + rh; row < NN; row += gridDim.x * 2) {
    float v = accum[row * NC + c];
    s += v;
    ss += v * v;
  }
  sh[threadIdx.x] = s;
  sh2[threadIdx.x] = ss;
  __syncthreads();
  if (threadIdx.x < 128) {
    s = sh[threadIdx.x] + sh[threadIdx.x + 128];
    ss = sh2[threadIdx.x] + sh2[threadIdx.x + 128];
    atomicAdd(&gsum[c], s);
    atomicAdd(&gsumsq[c], ss);
  }
}

// ---- BatchNorm (training stats) + ReLU -> fp32 ----------------------------
__global__ __launch_bounds__(256) void k_bn(
    const float* __restrict__ accum, const float* __restrict__ gsum,
    const float* __restrict__ gsumsq, const float* __restrict__ gamma,
    const float* __restrict__ beta, float* __restrict__ out) {
  int idx = blockIdx.x * 256 + threadIdx.x;
  if (idx >= NN * NC) return;
  int c = idx & 127;
  float mean = gsum[c] * (1.0f / NN);
  float var = gsumsq[c] * (1.0f / NN) - mean * mean;
  float inv = rsqrtf(var + BN_EPS);
  float y = (accum[idx] - mean) * inv * gamma[c] + beta[c];
  out[idx] = (y > 0.f) ? y : 0.f;
}

extern "C" void kernel_launch(void* const* d_in, const int* in_sizes, int n_in,
                              void* d_out, int out_size, void* d_ws, size_t ws_size,
                              hipStream_t stream) {
  const float* x    = (const float*)d_in[0];
  const void*  ei   = d_in[1];
  // d_in[2] = edge_attr (ignored: edge_dim=None in reference)
  const float* W    = (const float*)d_in[3];
  const float* attS = (const float*)d_in[4];
  const float* attD = (const float*)d_in[5];
  // d_in[6] = bias: cancels under BN mean-subtraction (and is zeros)
  const float* gamma = (const float*)d_in[7];
  const float* beta  = (const float*)d_in[8];

  float* ws     = (float*)d_ws;
  u16*   h      = (u16*)(ws + OFF_H);
  float* accum  = ws + OFF_ACCUM;
  float* a_src  = ws + OFF_ASRC;
  float* a_dst  = ws + OFF_ADST;
  int*   deg    = (int*)(ws + OFF_DEG);
  float* gsum   = ws + OFF_GSUM;
  float* gsumsq = ws + OFF_GSUMSQ;
  int*   rowptr = (int*)(ws + OFF_ROWPTR);
  int*   cursor = (int*)(ws + OFF_CURSOR);
  int*   bsum   = (int*)(ws + OFF_BSUM);
  int*   boff   = (int*)(ws + OFF_BOFF);
  int*   esrc   = (int*)(ws + OFF_ESRC);

  // zero deg + gsum + gsumsq
  hipMemsetAsync(deg, 0, (size_t)(OFF_ROWPTR - OFF_DEG) * sizeof(float), stream);

  const int nscan = (NN + 255) / 256;  // 196
  k_deg<<<(NE + 255) / 256, 256, 0, stream>>>(ei, deg);
  k_gemm<<<(NN + 63) / 64, 256, 0, stream>>>(x, W, attS, attD, h, a_src, a_dst);
  k_scan1<<<nscan, 256, 0, stream>>>(deg, rowptr, bsum);
  k_scan2<<<1, 256, 0, stream>>>(bsum, boff, nscan);
  k_scan3<<<nscan, 256, 0, stream>>>(rowptr, cursor, boff);
  k_fill<<<(NE + 255) / 256, 256, 0, stream>>>(ei, cursor, esrc);
  k_aggregate<<<(NN + 3) / 4, 256, 0, stream>>>(rowptr, esrc, a_src, a_dst, h, accum);
  k_stats<<<512, 256, 0, stream>>>(accum, gsum, gsumsq);
  k_bn<<<(NN * NC + 255) / 256, 256, 0, stream>>>(accum, gsum, gsumsq, gamma, beta,
                                                  (float*)d_out);
}

// Round 8
// 164.400 us; speedup vs baseline: 3.4571x; 1.3334x over previous
//
#include <hip/hip_runtime.h>
#include <hip/hip_bf16.h>

#define NN 50000
#define NE 800000
#define NC 128
#define NEG 0.2f
#define BN_EPS 1e-5f
#define NB 391           // ceil(NN/128) dst-buckets, 128 nodes each
#define EPB 2048         // edges per binning block
#define DEPTH 16         // LDS staging depth per bucket (flush = 64B line)

typedef unsigned int u32;
typedef unsigned short u16;
typedef short bf16x8 __attribute__((ext_vector_type(8)));
typedef float f32x4 __attribute__((ext_vector_type(4)));

// workspace layout (4-byte units)
#define OFF_H       0          // NN*NC bf16
#define OFF_ACCUM   3200000    // NN*NC f32
#define OFF_ASRC    9600000    // NN
#define OFF_ADST    9650000    // NN
#define OFF_BCNT    9700000    // 512   <- zeroed from here
#define OFF_GCUR    9700512    // 512
#define OFF_GSUM    9701024    // 128
#define OFF_GSUMSQ  9701152    // 128   <- zeroed to here
#define OFF_BBASE   9701280    // 400 (NB+1)
#define OFF_ROWPTR  9701680    // NN+1
#define OFF_ESRC    9751688    // NE
#define OFF_WGT     10551688   // NE
#define OFF_BIN     11351688   // NE
#define OFF_END     12151688   // ~48.6 MB

__device__ __forceinline__ float leaky(float e) { return (e >= 0.f) ? e : NEG * e; }

__device__ __forceinline__ u16 f2b(float f) {   // fp32 -> bf16 RNE
  union { float f; u32 u; } v; v.f = f;
  u32 u = v.u;
  return (u16)((u + 0x7fffu + ((u >> 16) & 1u)) >> 16);
}
__device__ __forceinline__ float blo(u32 u) {
  union { u32 u; float f; } v; v.u = u << 16; return v.f;
}
__device__ __forceinline__ float bhi(u32 u) {
  union { u32 u; float f; } v; v.u = u & 0xffff0000u; return v.f;
}

__device__ __forceinline__ bool ei_is64(const void* ei_raw) {
  const unsigned long long* p64 = (const unsigned long long*)ei_raw;
  bool is64 = true;
#pragma unroll
  for (int k = 0; k < 8; ++k) is64 = is64 && (p64[k] < (unsigned long long)NN);
  return is64;
}

// ---- h = x@W via MFMA bf16; fused a_src/a_dst; h stored bf16 --------------
__global__ __launch_bounds__(256) void k_gemm(
    const float* __restrict__ x, const float* __restrict__ W,
    const float* __restrict__ attS, const float* __restrict__ attD,
    u16* __restrict__ h, float* __restrict__ a_src, float* __restrict__ a_dst) {
  __shared__ u16 Wt[NC * NC];      // 32 KB
  const int t = threadIdx.x;
  const int l = t & 63;
  const int r0 = blockIdx.x * 64 + (t >> 6) * 16;

  for (int p = t; p < 8192; p += 256) {
    int col = p >> 6;
    int k = (p & 63) * 2;
    float w0 = W[k * NC + col];
    float w1 = W[(k + 1) * NC + col];
    u32 packed = ((u32)f2b(w1) << 16) | f2b(w0);
    int byte = col * 256 + ((k * 2) ^ ((col & 7) << 4));
    *(u32*)((char*)Wt + byte) = packed;
  }
  __syncthreads();

  const int arow = r0 + (l & 15);
  const bool aok = arow < NN;
  const int kg = l >> 4;
  const float* xa = x + (size_t)arow * NC + kg * 8;

  f32x4 acc[8];
#pragma unroll
  for (int n = 0; n < 8; ++n) acc[n] = (f32x4){0.f, 0.f, 0.f, 0.f};

  const int bbase0 = (l & 15) * 256;

#pragma unroll
  for (int s = 0; s < 4; ++s) {
    f32x4 a0 = (f32x4){0.f,0.f,0.f,0.f}, a1 = a0;
    if (aok) {
      a0 = *(const f32x4*)(xa + s * 32);
      a1 = *(const f32x4*)(xa + s * 32 + 4);
    }
    bf16x8 af;
    af[0]=(short)f2b(a0[0]); af[1]=(short)f2b(a0[1]);
    af[2]=(short)f2b(a0[2]); af[3]=(short)f2b(a0[3]);
    af[4]=(short)f2b(a1[0]); af[5]=(short)f2b(a1[1]);
    af[6]=(short)f2b(a1[2]); af[7]=(short)f2b(a1[3]);

    int kb2 = 16 * (s * 4 + kg);
    int boff = bbase0 + (kb2 ^ ((l & 7) << 4));
#pragma unroll
    for (int n = 0; n < 8; ++n) {
      bf16x8 bf = *(const bf16x8*)((const char*)Wt + boff + n * 4096);
      acc[n] = __builtin_amdgcn_mfma_f32_16x16x32_bf16(af, bf, acc[n], 0, 0, 0);
    }
  }

  float attS_r[8], attD_r[8];
#pragma unroll
  for (int n = 0; n < 8; ++n) {
    attS_r[n] = attS[16 * n + (l & 15)];
    attD_r[n] = attD[16 * n + (l & 15)];
  }
#pragma unroll
  for (int q = 0; q < 4; ++q) {
    int row = r0 + kg * 4 + q;
    bool rok = row < NN;
    float sA = 0.f, sD = 0.f;
#pragma unroll
    for (int n = 0; n < 8; ++n) {
      float v = acc[n][q];
      sA += v * attS_r[n];
      sD += v * attD_r[n];
      if (rok) h[(size_t)row * NC + 16 * n + (l & 15)] = f2b(v);
    }
    sA += __shfl_xor(sA, 1); sD += __shfl_xor(sD, 1);
    sA += __shfl_xor(sA, 2); sD += __shfl_xor(sD, 2);
    sA += __shfl_xor(sA, 4); sD += __shfl_xor(sD, 4);
    sA += __shfl_xor(sA, 8); sD += __shfl_xor(sD, 8);
    if ((l & 15) == 0 && rok) { a_src[row] = sA; a_dst[row] = sD; }
  }
}

// ---- bucket histogram (LDS-staged) ----------------------------------------
__global__ __launch_bounds__(256) void k_bhist(
    const void* __restrict__ ei_raw, int* __restrict__ bcnt) {
  __shared__ int cnt[NB];
  int t = threadIdx.x;
  for (int i = t; i < NB; i += 256) cnt[i] = 0;
  __syncthreads();
  bool is64 = ei_is64(ei_raw);
  int base = blockIdx.x * EPB;
#pragma unroll
  for (int k = 0; k < 8; ++k) {
    int idx = base + k * 256 + t;
    if (idx < NE) {
      int d = is64 ? (int)((const long long*)ei_raw)[NE + idx]
                   : ((const int*)ei_raw)[NE + idx];
      atomicAdd(&cnt[d >> 7], 1);
    }
  }
  __syncthreads();
  for (int i = t; i < NB; i += 256)
    if (cnt[i] > 0) atomicAdd(&bcnt[i], cnt[i]);
}

// ---- bucket-base exclusive scan (one block) -------------------------------
__global__ __launch_bounds__(512) void k_bscan(
    const int* __restrict__ bcnt, int* __restrict__ bbase) {
  __shared__ int sh[512];
  int t = threadIdx.x;
  int v = (t < NB) ? bcnt[t] : 0;
  sh[t] = v;
  __syncthreads();
  for (int off = 1; off < 512; off <<= 1) {
    int xv = (t >= off) ? sh[t - off] : 0;
    __syncthreads();
    sh[t] += xv;
    __syncthreads();
  }
  if (t <= NB) bbase[t] = sh[t] - v;   // exclusive; bbase[NB] = NE
}

// ---- bin edges into buckets, LDS-staged coalesced flushes -----------------
// pack = src | (dst&127)<<16  (src < 2^16)
__global__ __launch_bounds__(256) void k_bin(
    const void* __restrict__ ei_raw, const int* __restrict__ bbase,
    int* __restrict__ gcur, u32* __restrict__ bin) {
  __shared__ int cnt[NB];
  __shared__ u32 buf[NB * DEPTH];   // 25 KB
  int t = threadIdx.x;
  for (int i = t; i < NB; i += 256) cnt[i] = 0;
  __syncthreads();
  bool is64 = ei_is64(ei_raw);
  int base = blockIdx.x * EPB;
#pragma unroll
  for (int k = 0; k < 8; ++k) {
    int idx = base + k * 256 + t;
    if (idx >= NE) continue;
    int s, d;
    if (is64) {
      s = (int)((const long long*)ei_raw)[idx];
      d = (int)((const long long*)ei_raw)[NE + idx];
    } else {
      s = ((const int*)ei_raw)[idx];
      d = ((const int*)ei_raw)[NE + idx];
    }
    int b = d >> 7;
    u32 pack = (u32)s | ((u32)(d & 127) << 16);
    int p = atomicAdd(&cnt[b], 1);
    if (p < DEPTH) buf[b * DEPTH + p] = pack;
    else {               // rare overflow: direct scattered write
      int g = atomicAdd(&gcur[b], 1);
      bin[bbase[b] + g] = pack;
    }
  }
  __syncthreads();
  for (int b = t; b < NB; b += 256) {
    int c = min(cnt[b], DEPTH);
    if (c > 0) {
      int g = atomicAdd(&gcur[b], c);
      int gp = bbase[b] + g;
#pragma unroll 4
      for (int i = 0; i < c; ++i) bin[gp + i] = buf[b * DEPTH + i];
    }
  }
}

// ---- per-bucket CSR build + weight precompute -----------------------------
__global__ __launch_bounds__(256) void k_build(
    const int* __restrict__ bbase, const u32* __restrict__ bin,
    const float* __restrict__ a_src, const float* __restrict__ a_dst,
    int* __restrict__ rowptr, int* __restrict__ esrc, float* __restrict__ wgt) {
  __shared__ int cnt[128], bs[128], cur[128];
  __shared__ float aDl[128];
  int t = threadIdx.x;
  int b = blockIdx.x;
  int nbase = b << 7;
  int nmax = min(128, NN - nbase);
  int ebeg = bbase[b], eend = bbase[b + 1];
  int E = eend - ebeg;
  if (t < 128) { cnt[t] = 0; if (t < nmax) aDl[t] = a_dst[nbase + t]; }
  __syncthreads();
  for (int i = t; i < E; i += 256)
    atomicAdd(&cnt[bin[ebeg + i] >> 16], 1);
  __syncthreads();
  if (t < 128) bs[t] = cnt[t];
  __syncthreads();
  for (int off = 1; off < 128; off <<= 1) {
    int xv = (t < 128 && t >= off) ? bs[t - off] : 0;
    __syncthreads();
    if (t < 128) bs[t] += xv;
    __syncthreads();
  }
  if (t < 128) {
    int ex = bs[t] - cnt[t];      // inclusive -> exclusive
    bs[t] = ex;
    cur[t] = 0;
    if (t < nmax) rowptr[nbase + t] = ebeg + ex;
  }
  if (b == NB - 1 && t == 0) rowptr[NN] = NE;
  __syncthreads();
  for (int i = t; i < E; i += 256) {
    u32 e = bin[ebeg + i];
    int s = e & 0xFFFF;
    int ld = e >> 16;
    int p = atomicAdd(&cur[ld], 1);
    int pos = ebeg + bs[ld] + p;          // within L2-resident 8KB window
    esrc[pos] = s;
    wgt[pos] = __expf(leaky(a_src[s] + aDl[ld]));
  }
}

// ---- per-dst gather, wave-per-node, 4-way-unrolled shuffle-broadcast ------
__global__ __launch_bounds__(256) void k_aggregate(
    const int* __restrict__ rowptr, const int* __restrict__ esrc,
    const float* __restrict__ wgt, const float* __restrict__ a_src,
    const float* __restrict__ a_dst, const u16* __restrict__ h,
    float* __restrict__ accum) {
  int d = blockIdx.x * 4 + (threadIdx.x >> 6);
  if (d >= NN) return;
  int l = threadIdx.x & 63;            // lane owns channels 2l, 2l+1
  int beg = rowptr[d], end = rowptr[d + 1];

  float2 ac0 = make_float2(0.f, 0.f), ac1 = ac0, ac2 = ac0, ac3 = ac0;
  float wpart = 0.f;

  for (int j0 = beg; j0 < end; j0 += 64) {
    int n = min(64, end - j0);
    int s = 0;
    float w = 0.f;
    if (l < n) {
      s = esrc[j0 + l];
      w = wgt[j0 + l];
      wpart += w;
    }
    int jj = 0;
    for (; jj + 4 <= n; jj += 4) {
      int s0 = __shfl(s, jj),     s1 = __shfl(s, jj + 1);
      int s2 = __shfl(s, jj + 2), s3 = __shfl(s, jj + 3);
      float w0 = __shfl(w, jj),     w1 = __shfl(w, jj + 1);
      float w2 = __shfl(w, jj + 2), w3 = __shfl(w, jj + 3);
      u32 h0 = *(const u32*)&h[(size_t)s0 * NC + 2 * l];
      u32 h1 = *(const u32*)&h[(size_t)s1 * NC + 2 * l];
      u32 h2 = *(const u32*)&h[(size_t)s2 * NC + 2 * l];
      u32 h3 = *(const u32*)&h[(size_t)s3 * NC + 2 * l];
      ac0.x += w0 * blo(h0); ac0.y += w0 * bhi(h0);
      ac1.x += w1 * blo(h1); ac1.y += w1 * bhi(h1);
      ac2.x += w2 * blo(h2); ac2.y += w2 * bhi(h2);
      ac3.x += w3 * blo(h3); ac3.y += w3 * bhi(h3);
    }
    for (; jj < n; ++jj) {
      int sj = __shfl(s, jj);
      float wj = __shfl(w, jj);
      u32 hw = *(const u32*)&h[(size_t)sj * NC + 2 * l];
      ac0.x += wj * blo(hw); ac0.y += wj * bhi(hw);
    }
  }

  for (int off = 32; off > 0; off >>= 1) wpart += __shfl_xor(wpart, off);

  // self loop
  float wself = __expf(leaky(a_src[d] + a_dst[d]));
  u32 hw = *(const u32*)&h[(size_t)d * NC + 2 * l];
  float accx = ac0.x + ac1.x + ac2.x + ac3.x + wself * blo(hw);
  float accy = ac0.y + ac1.y + ac2.y + ac3.y + wself * bhi(hw);

  float inv = 1.f / (wpart + wself);
  *(float2*)&accum[(size_t)d * NC + 2 * l] = make_float2(accx * inv, accy * inv);
}

// ---- per-channel sum / sumsq ----------------------------------------------
__global__ __launch_bounds__(256) void k_stats(
    const float* __restrict__ accum, float* __restrict__ gsum,
    float* __restrict__ gsumsq) {
  __shared__ float sh[256], sh2[256];
  int c = threadIdx.x & 127, rh = threadIdx.x >> 7;
  float s = 0.f, ss = 0.f;
  for (int row = blockIdx.x * 2 + rh; row < NN; row += gridDim.x * 2) {
    float v = accum[row * NC + c];
    s += v;
    ss += v * v;
  }
  sh[threadIdx.x] = s;
  sh2[threadIdx.x] = ss;
  __syncthreads();
  if (threadIdx.x < 128) {
    s = sh[threadIdx.x] + sh[threadIdx.x + 128];
    ss = sh2[threadIdx.x] + sh2[threadIdx.x + 128];
    atomicAdd(&gsum[c], s);
    atomicAdd(&gsumsq[c], ss);
  }
}

// ---- BatchNorm (training stats) + ReLU -> fp32 ----------------------------
__global__ __launch_bounds__(256) void k_bn(
    const float* __restrict__ accum, const float* __restrict__ gsum,
    const float* __restrict__ gsumsq, const float* __restrict__ gamma,
    const float* __restrict__ beta, float* __restrict__ out) {
  int idx = blockIdx.x * 256 + threadIdx.x;
  if (idx >= NN * NC) return;
  int c = idx & 127;
  float mean = gsum[c] * (1.0f / NN);
  float var = gsumsq[c] * (1.0f / NN) - mean * mean;
  float inv = rsqrtf(var + BN_EPS);
  float y = (accum[idx] - mean) * inv * gamma[c] + beta[c];
  out[idx] = (y > 0.f) ? y : 0.f;
}

extern "C" void kernel_launch(void* const* d_in, const int* in_sizes, int n_in,
                              void* d_out, int out_size, void* d_ws, size_t ws_size,
                              hipStream_t stream) {
  const float* x    = (const float*)d_in[0];
  const void*  ei   = d_in[1];
  // d_in[2] = edge_attr (ignored: edge_dim=None in reference)
  const float* W    = (const float*)d_in[3];
  const float* attS = (const float*)d_in[4];
  const float* attD = (const float*)d_in[5];
  // d_in[6] = bias: cancels under BN mean-subtraction (and is zeros)
  const float* gamma = (const float*)d_in[7];
  const float* beta  = (const float*)d_in[8];

  float* ws     = (float*)d_ws;
  u16*   h      = (u16*)(ws + OFF_H);
  float* accum  = ws + OFF_ACCUM;
  float* a_src  = ws + OFF_ASRC;
  float* a_dst  = ws + OFF_ADST;
  int*   bcnt   = (int*)(ws + OFF_BCNT);
  int*   gcur   = (int*)(ws + OFF_GCUR);
  float* gsum   = ws + OFF_GSUM;
  float* gsumsq = ws + OFF_GSUMSQ;
  int*   bbase  = (int*)(ws + OFF_BBASE);
  int*   rowptr = (int*)(ws + OFF_ROWPTR);
  int*   esrc   = (int*)(ws + OFF_ESRC);
  float* wgt    = ws + OFF_WGT;
  u32*   bin    = (u32*)(ws + OFF_BIN);

  // zero bcnt + gcur + gsum + gsumsq (contiguous)
  hipMemsetAsync(bcnt, 0, (size_t)(OFF_BBASE - OFF_BCNT) * sizeof(float), stream);

  const int nbin = (NE + EPB - 1) / EPB;  // 391
  k_gemm<<<(NN + 63) / 64, 256, 0, stream>>>(x, W, attS, attD, h, a_src, a_dst);
  k_bhist<<<nbin, 256, 0, stream>>>(ei, bcnt);
  k_bscan<<<1, 512, 0, stream>>>(bcnt, bbase);
  k_bin<<<nbin, 256, 0, stream>>>(ei, bbase, gcur, bin);
  k_build<<<NB, 256, 0, stream>>>(bbase, bin, a_src, a_dst, rowptr, esrc, wgt);
  k_aggregate<<<(NN + 3) / 4, 256, 0, stream>>>(rowptr, esrc, wgt, a_src, a_dst, h, accum);
  k_stats<<<512, 256, 0, stream>>>(accum, gsum, gsumsq);
  k_bn<<<(NN * NC + 255) / 256, 256, 0, stream>>>(accum, gsum, gsumsq, gamma, beta,
                                                  (float*)d_out);
}

// Round 9
// 140.654 us; speedup vs baseline: 4.0408x; 1.1688x over previous
//
#include <hip/hip_runtime.h>
#include <hip/hip_bf16.h>

#define NN 50000
#define NE 800000
#define NC 128
#define NEG 0.2f
#define BN_EPS 1e-5f
#define NB 391           // ceil(NN/128) dst-buckets, 128 nodes each
#define EPB 2048         // edges per binning block
#define DEPTH 16         // LDS staging depth per bucket (flush = 64B line)

typedef unsigned int u32;
typedef unsigned short u16;
typedef short bf16x8 __attribute__((ext_vector_type(8)));
typedef float f32x4 __attribute__((ext_vector_type(4)));

// workspace layout (4-byte units)
#define OFF_H       0          // NN*NC bf16
#define OFF_ACCUM   3200000    // NN*NC f32
#define OFF_ASRC    9600000    // NN
#define OFF_ADST    9650000    // NN
#define OFF_BCNT    9700000    // 512   <- zeroed from here
#define OFF_GCUR    9700512    // 512
#define OFF_GSUM    9701024    // 128
#define OFF_GSUMSQ  9701152    // 128   <- zeroed to here
#define OFF_BBASE   9701280    // 400 (NB+1)
#define OFF_ROWPTR  9701680    // NN+1
#define OFF_ESRC    9751688    // NE
#define OFF_WGT     10551688   // NE
#define OFF_BIN     11351688   // NE
#define OFF_WB      12151688   // 8192 u32 (W in bf16 MFMA-frag order, 32 KB)
#define OFF_END     12159880   // ~48.6 MB

__device__ __forceinline__ float leaky(float e) { return (e >= 0.f) ? e : NEG * e; }

__device__ __forceinline__ u16 f2b(float f) {   // fp32 -> bf16 RNE
  union { float f; u32 u; } v; v.f = f;
  u32 u = v.u;
  return (u16)((u + 0x7fffu + ((u >> 16) & 1u)) >> 16);
}
__device__ __forceinline__ float blo(u32 u) {
  union { u32 u; float f; } v; v.u = u << 16; return v.f;
}
__device__ __forceinline__ float bhi(u32 u) {
  union { u32 u; float f; } v; v.u = u & 0xffff0000u; return v.f;
}

__device__ __forceinline__ bool ei_is64(const void* ei_raw) {
  const unsigned long long* p64 = (const unsigned long long*)ei_raw;
  bool is64 = true;
#pragma unroll
  for (int k = 0; k < 8; ++k) is64 = is64 && (p64[k] < (unsigned long long)NN);
  return is64;
}

// ---- pack W (fp32 row-major) into MFMA B-fragment order, bf16 -------------
// frag f = n*4+s holds cols 16n..16n+15, k = 32s..32s+31.
// lane l of frag f: col = 16n+(l&15), k = 32s+8*(l>>4)+j (j=0..7).
// slot q = f*64+l -> 4 u32 at Wb32[q*4..q*4+3] (16B per lane, contiguous).
__global__ __launch_bounds__(256) void k_prep(
    const float* __restrict__ W, u32* __restrict__ Wb32) {
  int q = blockIdx.x * 256 + threadIdx.x;   // 2048 slots
  if (q >= 2048) return;
  int f = q >> 6, l = q & 63;
  int n = f >> 2, s = f & 3;
  int col = 16 * n + (l & 15);
  int kb = 32 * s + 8 * (l >> 4);
#pragma unroll
  for (int j2 = 0; j2 < 4; ++j2) {
    u16 e0 = f2b(W[(kb + 2 * j2) * NC + col]);
    u16 e1 = f2b(W[(kb + 2 * j2 + 1) * NC + col]);
    Wb32[q * 4 + j2] = ((u32)e1 << 16) | e0;
  }
}

// ---- h = x@W via MFMA bf16, B-frags from global (no LDS, no syncs) --------
// block = 256 thr = 4 waves; wave handles 32 rows (2 tiles of 16).
__global__ __launch_bounds__(256) void k_gemm(
    const float* __restrict__ x, const u16* __restrict__ Wb,
    const float* __restrict__ attS, const float* __restrict__ attD,
    u16* __restrict__ h, float* __restrict__ a_src, float* __restrict__ a_dst) {
  const int t = threadIdx.x;
  const int l = t & 63;
  const int r0 = blockIdx.x * 128 + (t >> 6) * 32;
  const int lr = l & 15;                  // row-in-tile / col-in-frag
  const int kg = l >> 4;                  // k-group

  f32x4 acc[2][8];
#pragma unroll
  for (int t2 = 0; t2 < 2; ++t2)
#pragma unroll
    for (int n = 0; n < 8; ++n) acc[t2][n] = (f32x4){0.f, 0.f, 0.f, 0.f};

#pragma unroll
  for (int s = 0; s < 4; ++s) {
    bf16x8 bfr[8];
#pragma unroll
    for (int n = 0; n < 8; ++n)
      bfr[n] = *(const bf16x8*)(Wb + ((size_t)((n * 4 + s) * 64 + l)) * 8);

#pragma unroll
    for (int t2 = 0; t2 < 2; ++t2) {
      int arow = r0 + t2 * 16 + lr;
      f32x4 a0 = (f32x4){0.f,0.f,0.f,0.f}, a1 = a0;
      if (arow < NN) {
        const float* xa = x + (size_t)arow * NC + kg * 8 + s * 32;
        a0 = *(const f32x4*)xa;
        a1 = *(const f32x4*)(xa + 4);
      }
      bf16x8 af;
      af[0]=(short)f2b(a0[0]); af[1]=(short)f2b(a0[1]);
      af[2]=(short)f2b(a0[2]); af[3]=(short)f2b(a0[3]);
      af[4]=(short)f2b(a1[0]); af[5]=(short)f2b(a1[1]);
      af[6]=(short)f2b(a1[2]); af[7]=(short)f2b(a1[3]);
#pragma unroll
      for (int n = 0; n < 8; ++n)
        acc[t2][n] = __builtin_amdgcn_mfma_f32_16x16x32_bf16(af, bfr[n], acc[t2][n], 0, 0, 0);
    }
  }

  float attS_r[8], attD_r[8];
#pragma unroll
  for (int n = 0; n < 8; ++n) {
    attS_r[n] = attS[16 * n + lr];
    attD_r[n] = attD[16 * n + lr];
  }
#pragma unroll
  for (int t2 = 0; t2 < 2; ++t2) {
#pragma unroll
    for (int q = 0; q < 4; ++q) {
      int row = r0 + t2 * 16 + kg * 4 + q;
      bool rok = row < NN;
      float sA = 0.f, sD = 0.f;
#pragma unroll
      for (int n = 0; n < 8; ++n) {
        float v = acc[t2][n][q];
        sA += v * attS_r[n];
        sD += v * attD_r[n];
        if (rok) h[(size_t)row * NC + 16 * n + lr] = f2b(v);
      }
      sA += __shfl_xor(sA, 1); sD += __shfl_xor(sD, 1);
      sA += __shfl_xor(sA, 2); sD += __shfl_xor(sD, 2);
      sA += __shfl_xor(sA, 4); sD += __shfl_xor(sD, 4);
      sA += __shfl_xor(sA, 8); sD += __shfl_xor(sD, 8);
      if (lr == 0 && rok) { a_src[row] = sA; a_dst[row] = sD; }
    }
  }
}

// ---- bucket histogram (LDS-staged) ----------------------------------------
__global__ __launch_bounds__(256) void k_bhist(
    const void* __restrict__ ei_raw, int* __restrict__ bcnt) {
  __shared__ int cnt[NB];
  int t = threadIdx.x;
  for (int i = t; i < NB; i += 256) cnt[i] = 0;
  __syncthreads();
  bool is64 = ei_is64(ei_raw);
  int base = blockIdx.x * EPB;
#pragma unroll
  for (int k = 0; k < 8; ++k) {
    int idx = base + k * 256 + t;
    if (idx < NE) {
      int d = is64 ? (int)((const long long*)ei_raw)[NE + idx]
                   : ((const int*)ei_raw)[NE + idx];
      atomicAdd(&cnt[d >> 7], 1);
    }
  }
  __syncthreads();
  for (int i = t; i < NB; i += 256)
    if (cnt[i] > 0) atomicAdd(&bcnt[i], cnt[i]);
}

// ---- bucket-base exclusive scan (one block) -------------------------------
__global__ __launch_bounds__(512) void k_bscan(
    const int* __restrict__ bcnt, int* __restrict__ bbase) {
  __shared__ int sh[512];
  int t = threadIdx.x;
  int v = (t < NB) ? bcnt[t] : 0;
  sh[t] = v;
  __syncthreads();
  for (int off = 1; off < 512; off <<= 1) {
    int xv = (t >= off) ? sh[t - off] : 0;
    __syncthreads();
    sh[t] += xv;
    __syncthreads();
  }
  if (t <= NB) bbase[t] = sh[t] - v;   // exclusive; bbase[NB] = NE
}

// ---- bin edges into buckets, LDS-staged coalesced flushes -----------------
// pack = src | (dst&127)<<16  (src < 2^16)
__global__ __launch_bounds__(256) void k_bin(
    const void* __restrict__ ei_raw, const int* __restrict__ bbase,
    int* __restrict__ gcur, u32* __restrict__ bin) {
  __shared__ int cnt[NB];
  __shared__ u32 buf[NB * DEPTH];   // 25 KB
  int t = threadIdx.x;
  for (int i = t; i < NB; i += 256) cnt[i] = 0;
  __syncthreads();
  bool is64 = ei_is64(ei_raw);
  int base = blockIdx.x * EPB;
#pragma unroll
  for (int k = 0; k < 8; ++k) {
    int idx = base + k * 256 + t;
    if (idx >= NE) continue;
    int s, d;
    if (is64) {
      s = (int)((const long long*)ei_raw)[idx];
      d = (int)((const long long*)ei_raw)[NE + idx];
    } else {
      s = ((const int*)ei_raw)[idx];
      d = ((const int*)ei_raw)[NE + idx];
    }
    int b = d >> 7;
    u32 pack = (u32)s | ((u32)(d & 127) << 16);
    int p = atomicAdd(&cnt[b], 1);
    if (p < DEPTH) buf[b * DEPTH + p] = pack;
    else {               // rare overflow: direct scattered write
      int g = atomicAdd(&gcur[b], 1);
      bin[bbase[b] + g] = pack;
    }
  }
  __syncthreads();
  for (int b = t; b < NB; b += 256) {
    int c = min(cnt[b], DEPTH);
    if (c > 0) {
      int g = atomicAdd(&gcur[b], c);
      int gp = bbase[b] + g;
#pragma unroll 4
      for (int i = 0; i < c; ++i) bin[gp + i] = buf[b * DEPTH + i];
    }
  }
}

// ---- per-bucket CSR build + weight precompute -----------------------------
__global__ __launch_bounds__(256) void k_build(
    const int* __restrict__ bbase, const u32* __restrict__ bin,
    const float* __restrict__ a_src, const float* __restrict__ a_dst,
    int* __restrict__ rowptr, int* __restrict__ esrc, float* __restrict__ wgt) {
  __shared__ int cnt[128], bs[128], cur[128];
  __shared__ float aDl[128];
  int t = threadIdx.x;
  int b = blockIdx.x;
  int nbase = b << 7;
  int nmax = min(128, NN - nbase);
  int ebeg = bbase[b], eend = bbase[b + 1];
  int E = eend - ebeg;
  if (t < 128) { cnt[t] = 0; if (t < nmax) aDl[t] = a_dst[nbase + t]; }
  __syncthreads();
  for (int i = t; i < E; i += 256)
    atomicAdd(&cnt[bin[ebeg + i] >> 16], 1);
  __syncthreads();
  if (t < 128) bs[t] = cnt[t];
  __syncthreads();
  for (int off = 1; off < 128; off <<= 1) {
    int xv = (t < 128 && t >= off) ? bs[t - off] : 0;
    __syncthreads();
    if (t < 128) bs[t] += xv;
    __syncthreads();
  }
  if (t < 128) {
    int ex = bs[t] - cnt[t];      // inclusive -> exclusive
    bs[t] = ex;
    cur[t] = 0;
    if (t < nmax) rowptr[nbase + t] = ebeg + ex;
  }
  if (b == NB - 1 && t == 0) rowptr[NN] = NE;
  __syncthreads();
  for (int i = t; i < E; i += 256) {
    u32 e = bin[ebeg + i];
    int s = e & 0xFFFF;
    int ld = e >> 16;
    int p = atomicAdd(&cur[ld], 1);
    int pos = ebeg + bs[ld] + p;          // within L2-resident 8KB window
    esrc[pos] = s;
    wgt[pos] = __expf(leaky(a_src[s] + aDl[ld]));
  }
}

// ---- per-dst gather, wave-per-node, 4-way-unrolled shuffle-broadcast ------
__global__ __launch_bounds__(256) void k_aggregate(
    const int* __restrict__ rowptr, const int* __restrict__ esrc,
    const float* __restrict__ wgt, const float* __restrict__ a_src,
    const float* __restrict__ a_dst, const u16* __restrict__ h,
    float* __restrict__ accum) {
  int d = blockIdx.x * 4 + (threadIdx.x >> 6);
  if (d >= NN) return;
  int l = threadIdx.x & 63;            // lane owns channels 2l, 2l+1
  int beg = rowptr[d], end = rowptr[d + 1];

  float2 ac0 = make_float2(0.f, 0.f), ac1 = ac0, ac2 = ac0, ac3 = ac0;
  float wpart = 0.f;

  for (int j0 = beg; j0 < end; j0 += 64) {
    int n = min(64, end - j0);
    int s = 0;
    float w = 0.f;
    if (l < n) {
      s = esrc[j0 + l];
      w = wgt[j0 + l];
      wpart += w;
    }
    int jj = 0;
    for (; jj + 4 <= n; jj += 4) {
      int s0 = __shfl(s, jj),     s1 = __shfl(s, jj + 1);
      int s2 = __shfl(s, jj + 2), s3 = __shfl(s, jj + 3);
      float w0 = __shfl(w, jj),     w1 = __shfl(w, jj + 1);
      float w2 = __shfl(w, jj + 2), w3 = __shfl(w, jj + 3);
      u32 h0 = *(const u32*)&h[(size_t)s0 * NC + 2 * l];
      u32 h1 = *(const u32*)&h[(size_t)s1 * NC + 2 * l];
      u32 h2 = *(const u32*)&h[(size_t)s2 * NC + 2 * l];
      u32 h3 = *(const u32*)&h[(size_t)s3 * NC + 2 * l];
      ac0.x += w0 * blo(h0); ac0.y += w0 * bhi(h0);
      ac1.x += w1 * blo(h1); ac1.y += w1 * bhi(h1);
      ac2.x += w2 * blo(h2); ac2.y += w2 * bhi(h2);
      ac3.x += w3 * blo(h3); ac3.y += w3 * bhi(h3);
    }
    for (; jj < n; ++jj) {
      int sj = __shfl(s, jj);
      float wj = __shfl(w, jj);
      u32 hw = *(const u32*)&h[(size_t)sj * NC + 2 * l];
      ac0.x += wj * blo(hw); ac0.y += wj * bhi(hw);
    }
  }

  for (int off = 32; off > 0; off >>= 1) wpart += __shfl_xor(wpart, off);

  // self loop
  float wself = __expf(leaky(a_src[d] + a_dst[d]));
  u32 hw = *(const u32*)&h[(size_t)d * NC + 2 * l];
  float accx = ac0.x + ac1.x + ac2.x + ac3.x + wself * blo(hw);
  float accy = ac0.y + ac1.y + ac2.y + ac3.y + wself * bhi(hw);

  float inv = 1.f / (wpart + wself);
  *(float2*)&accum[(size_t)d * NC + 2 * l] = make_float2(accx * inv, accy * inv);
}

// ---- per-channel sum / sumsq ----------------------------------------------
__global__ __launch_bounds__(256) void k_stats(
    const float* __restrict__ accum, float* __restrict__ gsum,
    float* __restrict__ gsumsq) {
  __shared__ float sh[256], sh2[256];
  int c = threadIdx.x & 127, rh = threadIdx.x >> 7;
  float s = 0.f, ss = 0.f;
  for (int row = blockIdx.x * 2 + rh; row < NN; row += gridDim.x * 2) {
    float v = accum[row * NC + c];
    s += v;
    ss += v * v;
  }
  sh[threadIdx.x] = s;
  sh2[threadIdx.x] = ss;
  __syncthreads();
  if (threadIdx.x < 128) {
    s = sh[threadIdx.x] + sh[threadIdx.x + 128];
    ss = sh2[threadIdx.x] + sh2[threadIdx.x + 128];
    atomicAdd(&gsum[c], s);
    atomicAdd(&gsumsq[c], ss);
  }
}

// ---- BatchNorm (training stats) + ReLU -> fp32 ----------------------------
__global__ __launch_bounds__(256) void k_bn(
    const float* __restrict__ accum, const float* __restrict__ gsum,
    const float* __restrict__ gsumsq, const float* __restrict__ gamma,
    const float* __restrict__ beta, float* __restrict__ out) {
  int idx = blockIdx.x * 256 + threadIdx.x;
  if (idx >= NN * NC) return;
  int c = idx & 127;
  float mean = gsum[c] * (1.0f / NN);
  float var = gsumsq[c] * (1.0f / NN) - mean * mean;
  float inv = rsqrtf(var + BN_EPS);
  float y = (accum[idx] - mean) * inv * gamma[c] + beta[c];
  out[idx] = (y > 0.f) ? y : 0.f;
}

extern "C" void kernel_launch(void* const* d_in, const int* in_sizes, int n_in,
                              void* d_out, int out_size, void* d_ws, size_t ws_size,
                              hipStream_t stream) {
  const float* x    = (const float*)d_in[0];
  const void*  ei   = d_in[1];
  // d_in[2] = edge_attr (ignored: edge_dim=None in reference)
  const float* W    = (const float*)d_in[3];
  const float* attS = (const float*)d_in[4];
  const float* attD = (const float*)d_in[5];
  // d_in[6] = bias: cancels under BN mean-subtraction (and is zeros)
  const float* gamma = (const float*)d_in[7];
  const float* beta  = (const float*)d_in[8];

  float* ws     = (float*)d_ws;
  u16*   h      = (u16*)(ws + OFF_H);
  float* accum  = ws + OFF_ACCUM;
  float* a_src  = ws + OFF_ASRC;
  float* a_dst  = ws + OFF_ADST;
  int*   bcnt   = (int*)(ws + OFF_BCNT);
  int*   gcur   = (int*)(ws + OFF_GCUR);
  float* gsum   = ws + OFF_GSUM;
  float* gsumsq = ws + OFF_GSUMSQ;
  int*   bbase  = (int*)(ws + OFF_BBASE);
  int*   rowptr = (int*)(ws + OFF_ROWPTR);
  int*   esrc   = (int*)(ws + OFF_ESRC);
  float* wgt    = ws + OFF_WGT;
  u32*   bin    = (u32*)(ws + OFF_BIN);
  u32*   wb32   = (u32*)(ws + OFF_WB);

  // zero bcnt + gcur + gsum + gsumsq (contiguous)
  hipMemsetAsync(bcnt, 0, (size_t)(OFF_BBASE - OFF_BCNT) * sizeof(float), stream);

  const int nbin = (NE + EPB - 1) / EPB;  // 391
  k_prep<<<8, 256, 0, stream>>>(W, wb32);
  k_gemm<<<(NN + 127) / 128, 256, 0, stream>>>(x, (const u16*)wb32, attS, attD,
                                               h, a_src, a_dst);
  k_bhist<<<nbin, 256, 0, stream>>>(ei, bcnt);
  k_bscan<<<1, 512, 0, stream>>>(bcnt, bbase);
  k_bin<<<nbin, 256, 0, stream>>>(ei, bbase, gcur, bin);
  k_build<<<NB, 256, 0, stream>>>(bbase, bin, a_src, a_dst, rowptr, esrc, wgt);
  k_aggregate<<<(NN + 3) / 4, 256, 0, stream>>>(rowptr, esrc, wgt, a_src, a_dst, h, accum);
  k_stats<<<512, 256, 0, stream>>>(accum, gsum, gsumsq);
  k_bn<<<(NN * NC + 255) / 256, 256, 0, stream>>>(accum, gsum, gsumsq, gamma, beta,
                                                  (float*)d_out);
}